// Round 1
// baseline (1126.903 us; speedup 1.0000x reference)
//
#include <hip/hip_runtime.h>
#include <stdint.h>

typedef unsigned long long u64;
typedef unsigned int u32;

#define NCC 80
#define NPRED 25200
#define NBI 32
#define NELEM (NPRED * NCC)   // 2016000
#define KCAND 2048
#define MAXDET 300
#define CONF 0.001f
#define IOU_T 0.6f
#define MAXWH 4096.0f
#define CAPC 16384
#define NBINS 4096
#define SORTN 4096
#define HIST_LO 0.5f
#define HIST_SCALE 8192.0f
#define COLLECT_T 0.93f
#define BSTAR_SAFE 3523       // bin >= 3523 -> lower edge 0.93005 > 0.93

// workspace layout (bytes)
static const size_t OFF_HIST  = 0;                                   // 32*4096*4 = 524288
static const size_t OFF_CNT   = 524288;
static const size_t OFF_BSTAR = 524288 + 512;
static const size_t OFF_FLAG  = 524288 + 1024;
static const size_t OFF_CAND  = 528384;                              // + 32*16384*8 = 4194304
static const size_t OFF_CBOX  = OFF_CAND + (size_t)NBI * CAPC * 8;   // + 32*2048*16
static const size_t OFF_CLS   = OFF_CBOX + (size_t)NBI * KCAND * 16; // + 32*2048*4
static const size_t OFF_SCORE = OFF_CLS + (size_t)NBI * KCAND * 4;   // + 32*2048*4
static const size_t OFF_OVER  = OFF_SCORE + (size_t)NBI * KCAND * 4; // + 32*2048*32*8

// ---------- Kernel 1: scores -> histogram (s>0.5) + collect (s>0.93) ----------
__global__ void k1_hist_collect(const float* __restrict__ pred,
                                u32* __restrict__ hist, u32* __restrict__ cnt,
                                u64* __restrict__ cand) {
    int b = blockIdx.y;
    __shared__ u32 lh[NBINS];
    for (int i = threadIdx.x; i < NBINS; i += blockDim.x) lh[i] = 0;
    __syncthreads();
    const float* p = pred + (size_t)b * NPRED * 85;
    int stride = gridDim.x * blockDim.x;
    for (int e = blockIdx.x * blockDim.x + threadIdx.x; e < NELEM; e += stride) {
        u32 n = (u32)e / NCC;
        u32 c = (u32)e - n * NCC;
        float obj = p[n * 85 + 4];
        float cv  = p[n * 85 + 5 + c];
        float s = obj * cv;
        if (s > HIST_LO) {
            int ib = (int)((s - HIST_LO) * HIST_SCALE);
            if (ib > NBINS - 1) ib = NBINS - 1;
            atomicAdd(&lh[ib], 1u);
            if (s > COLLECT_T) {
                u32 pos = atomicAdd(&cnt[b], 1u);
                if (pos < CAPC) {
                    u32 sb = __float_as_uint(s);
                    cand[(size_t)b * CAPC + pos] = ((u64)sb << 32) | (u32)(~(u32)e);
                }
            }
        }
    }
    __syncthreads();
    u32* gh = hist + (size_t)b * NBINS;
    for (int i = threadIdx.x; i < NBINS; i += blockDim.x) {
        u32 v = lh[i];
        if (v) atomicAdd(&gh[i], v);
    }
}

// ---------- Kernel 2: find exact threshold bin b* per image ----------
__global__ void k2_threshold(const u32* __restrict__ hist, u32* __restrict__ cnt,
                             int* __restrict__ bstar, int* __restrict__ flag) {
    int b = blockIdx.x;
    const u32* gh = hist + (size_t)b * NBINS;
    __shared__ u32 csum[256];
    u32 s = 0;
    for (int i = 0; i < 16; ++i) s += gh[threadIdx.x * 16 + i];
    csum[threadIdx.x] = s;
    __syncthreads();
    if (threadIdx.x == 0) {
        int bs = -1;
        u32 acc = 0; int cc = -1; u32 accBefore = 0;
        for (int c = 255; c >= 0; --c) {
            if (acc + csum[c] >= KCAND) { cc = c; accBefore = acc; break; }
            acc += csum[c];
        }
        if (cc >= 0) {
            u32 a2 = accBefore;
            for (int bi = cc * 16 + 15; bi >= cc * 16; --bi) {
                a2 += gh[bi];
                if (a2 >= KCAND) { bs = bi; break; }
            }
        }
        bool needfb;
        if (bs < 0) needfb = true;
        else needfb = (bs < BSTAR_SAFE) || (cnt[b] > CAPC);
        bstar[b] = bs;
        flag[b] = needfb ? 1 : 0;
        if (needfb) cnt[b] = 0;   // fallback kernel re-collects
    }
}

// ---------- Kernel 3: fallback collect (normally a no-op) ----------
__global__ void k3_fallback(const float* __restrict__ pred, u32* __restrict__ cnt,
                            u64* __restrict__ cand, const int* __restrict__ bstar,
                            const int* __restrict__ flag) {
    int b = blockIdx.y;
    if (!flag[b]) return;
    int bs = bstar[b];
    const float* p = pred + (size_t)b * NPRED * 85;
    int stride = gridDim.x * blockDim.x;
    for (int e = blockIdx.x * blockDim.x + threadIdx.x; e < NELEM; e += stride) {
        u32 n = (u32)e / NCC;
        u32 c = (u32)e - n * NCC;
        float obj = p[n * 85 + 4];
        float cv  = p[n * 85 + 5 + c];
        float s = obj * cv;
        bool take;
        if (bs < 0) take = (s > CONF);
        else take = (s > HIST_LO) && ((int)((s - HIST_LO) * HIST_SCALE) >= bs);
        if (take) {
            u32 pos = atomicAdd(&cnt[b], 1u);
            if (pos < CAPC) {
                u32 sb = __float_as_uint(s);
                cand[(size_t)b * CAPC + pos] = ((u64)sb << 32) | (u32)(~(u32)e);
            }
        }
    }
}

// ---------- Kernel 4: filter by bin>=b*, bitonic sort, take top-2048, gather boxes ----------
__global__ __launch_bounds__(1024) void k4_sort_gather(
        const float* __restrict__ pred, const u32* __restrict__ cnt,
        const u64* __restrict__ cand, const int* __restrict__ bstar,
        float4* __restrict__ cbox, float* __restrict__ clsArr, float* __restrict__ scoreArr) {
    int b = blockIdx.x;
    __shared__ u64 keys[SORTN];
    __shared__ u32 lcnt;
    if (threadIdx.x == 0) lcnt = 0;
    for (int i = threadIdx.x; i < SORTN; i += 1024) keys[i] = 0ULL;
    __syncthreads();
    int bs = bstar[b];
    u32 m = cnt[b]; if (m > CAPC) m = CAPC;
    for (u32 t = threadIdx.x; t < m; t += 1024) {
        u64 key = cand[(size_t)b * CAPC + t];
        float s = __uint_as_float((u32)(key >> 32));
        bool acc = (bs < 0) || ((s > HIST_LO) && ((int)((s - HIST_LO) * HIST_SCALE) >= bs));
        if (acc) {
            u32 pos = atomicAdd(&lcnt, 1u);
            if (pos < SORTN) keys[pos] = key;
        }
    }
    __syncthreads();
    // bitonic sort, descending on (score_bits, ~idx)
    for (int k = 2; k <= SORTN; k <<= 1) {
        for (int j = k >> 1; j > 0; j >>= 1) {
            for (int i = threadIdx.x; i < SORTN; i += 1024) {
                int ixj = i ^ j;
                if (ixj > i) {
                    u64 a = keys[i], bb = keys[ixj];
                    bool up = (i & k) == 0;
                    bool sw = up ? (a < bb) : (a > bb);
                    if (sw) { keys[i] = bb; keys[ixj] = a; }
                }
            }
            __syncthreads();
        }
    }
    const float* p = pred + (size_t)b * NPRED * 85;
    for (int t = threadIdx.x; t < KCAND; t += 1024) {
        u64 key = keys[t];
        float s = __uint_as_float((u32)(key >> 32));
        float4 cb; float cf; float sv;
        if (s > CONF) {
            u32 idx = ~(u32)key;
            u32 n = idx / NCC; u32 c = idx - n * NCC;
            float x = p[n * 85 + 0], y = p[n * 85 + 1];
            float w = p[n * 85 + 2], h = p[n * 85 + 3];
            float hw = w * 0.5f, hh = h * 0.5f;
            cb = make_float4(x - hw, y - hh, x + hw, y + hh);
            cf = (float)c; sv = s;
        } else {
            cb = make_float4(0.f, 0.f, 0.f, 0.f); cf = 0.f; sv = -1.f;
        }
        cbox[(size_t)b * KCAND + t] = cb;
        clsArr[(size_t)b * KCAND + t] = cf;
        scoreArr[(size_t)b * KCAND + t] = sv;
    }
}

// ---------- Kernel 5: IoU adjacency (only j > i bits), offset boxes like reference ----------
__global__ __launch_bounds__(1024) void k5_iou(const float4* __restrict__ cbox,
                                               const float* __restrict__ clsArr,
                                               u64* __restrict__ over) {
    int blk = blockIdx.x;          // 32 img * 64 row-blocks
    int b = blk >> 6;
    int rowBase = (blk & 63) << 5; // 32 rows per block
    __shared__ float ox1[KCAND], oy1[KCAND], ox2[KCAND], oy2[KCAND], oar[KCAND];
    for (int j = threadIdx.x; j < KCAND; j += 1024) {
        float4 cb = cbox[(size_t)b * KCAND + j];
        float off = clsArr[(size_t)b * KCAND + j] * MAXWH;
        float a = cb.x + off, c = cb.y + off, d = cb.z + off, e = cb.w + off;
        ox1[j] = a; oy1[j] = c; ox2[j] = d; oy2[j] = e;
        oar[j] = (d - a) * (e - c);   // area from offset coords, same as reference
    }
    __syncthreads();
    int w = threadIdx.x & 31;
    int r = threadIdx.x >> 5;
    int i = rowBase + r;
    float ix1 = ox1[i], iy1 = oy1[i], ix2 = ox2[i], iy2 = oy2[i], iar = oar[i];
    u64 bits = 0;
    int j0 = w << 6;
    if (j0 + 63 > i) {
        for (int jb = 0; jb < 64; ++jb) {
            int jj = (jb + w) & 63;         // rotate to avoid 32-way LDS bank conflicts
            int j = j0 + jj;
            if (j > i) {
                float lx = fmaxf(ix1, ox1[j]);
                float ly = fmaxf(iy1, oy1[j]);
                float rx = fminf(ix2, ox2[j]);
                float ry = fminf(iy2, oy2[j]);
                float iw = rx - lx; if (iw < 0.f) iw = 0.f;
                float ih = ry - ly; if (ih < 0.f) ih = 0.f;
                float inter = iw * ih;
                float uni = iar + oar[j] - inter;
                float iou = inter / uni;     // NaN for degenerate -> comparison false
                if (iou > IOU_T) bits |= (1ULL << jj);
            }
        }
    }
    over[((size_t)b * KCAND + i) * 32 + w] = bits;
}

// ---------- Kernel 6: greedy suppression over set bits + write output ----------
__global__ __launch_bounds__(64) void k6_nms_out(const float4* __restrict__ cbox,
                                                 const float* __restrict__ clsArr,
                                                 const float* __restrict__ scoreArr,
                                                 const u64* __restrict__ over,
                                                 float* __restrict__ out) {
    int b = blockIdx.x;
    int lane = threadIdx.x;
    __shared__ u64 keep[32];
    __shared__ unsigned short outl[MAXDET];
    const float* sc = scoreArr + (size_t)b * KCAND;
    for (int k = 0; k < 32; ++k) {
        u64 m = __ballot(sc[k * 64 + lane] > CONF);
        if (lane == k) keep[k] = m;
    }
    __syncthreads();
    int outc = 0;
    const u64* ov = over + (size_t)b * KCAND * 32;
    for (int w = 0; w < 32 && outc < MAXDET; ++w) {
        u64 m = keep[w];
        while (m && outc < MAXDET) {
            int t = __builtin_ctzll(m);
            int i = (w << 6) + t;
            if (lane == 0) outl[outc] = (unsigned short)i;
            outc++;
            u64 row = (lane < 32) ? ov[(size_t)i * 32 + lane] : 0ULL;
            if (lane < 32) keep[lane] &= ~row;   // row has only j>i bits
            __syncthreads();
            m = (t == 63) ? 0ULL : (keep[w] & (~0ULL << (t + 1)));
        }
    }
    __syncthreads();
    float* ob = out + (size_t)b * MAXDET * 6;
    for (int slot = lane; slot < MAXDET; slot += 64) {
        float v0 = 0.f, v1 = 0.f, v2 = 0.f, v3 = 0.f, v4 = 0.f, v5 = 0.f;
        if (slot < outc) {
            int i = outl[slot];
            float4 cb = cbox[(size_t)b * KCAND + i];
            v0 = cb.x; v1 = cb.y; v2 = cb.z; v3 = cb.w;
            v4 = sc[i];
            v5 = clsArr[(size_t)b * KCAND + i];
        }
        ob[slot * 6 + 0] = v0; ob[slot * 6 + 1] = v1; ob[slot * 6 + 2] = v2;
        ob[slot * 6 + 3] = v3; ob[slot * 6 + 4] = v4; ob[slot * 6 + 5] = v5;
    }
}

extern "C" void kernel_launch(void* const* d_in, const int* in_sizes, int n_in,
                              void* d_out, int out_size, void* d_ws, size_t ws_size,
                              hipStream_t stream) {
    const float* pred = (const float*)d_in[0];
    float* out = (float*)d_out;
    uint8_t* ws = (uint8_t*)d_ws;

    u32* hist   = (u32*)(ws + OFF_HIST);
    u32* cnt    = (u32*)(ws + OFF_CNT);
    int* bstar  = (int*)(ws + OFF_BSTAR);
    int* flag   = (int*)(ws + OFF_FLAG);
    u64* cand   = (u64*)(ws + OFF_CAND);
    float4* cbox   = (float4*)(ws + OFF_CBOX);
    float* clsArr  = (float*)(ws + OFF_CLS);
    float* scoreArr= (float*)(ws + OFF_SCORE);
    u64* over   = (u64*)(ws + OFF_OVER);

    // zero hist + counters (rest is fully overwritten where read)
    hipMemsetAsync(ws, 0, OFF_CAND, stream);

    dim3 g1(252, NBI);
    k1_hist_collect<<<g1, 256, 0, stream>>>(pred, hist, cnt, cand);
    k2_threshold<<<NBI, 256, 0, stream>>>(hist, cnt, bstar, flag);
    k3_fallback<<<g1, 256, 0, stream>>>(pred, cnt, cand, bstar, flag);
    k4_sort_gather<<<NBI, 1024, 0, stream>>>(pred, cnt, cand, bstar, cbox, clsArr, scoreArr);
    k5_iou<<<NBI * 64, 1024, 0, stream>>>(cbox, clsArr, over);
    k6_nms_out<<<NBI, 64, 0, stream>>>(cbox, clsArr, scoreArr, over, out);
}

// Round 2
// 456.829 us; speedup vs baseline: 2.4668x; 2.4668x over previous
//
#include <hip/hip_runtime.h>
#include <stdint.h>

typedef unsigned long long u64;
typedef unsigned int u32;

#define NCC 80
#define NPRED 25200
#define NBI 32
#define NELEM (NPRED * NCC)   // 2016000
#define KCAND 2048
#define MAXDET 300
#define CONF 0.001f
#define IOU_T 0.6f
#define MAXWH 4096.0f
#define CAPC 16384
#define NBINS 4096
#define SORTN 4096
#define HIST_LO 0.5f
#define HIST_SCALE 8192.0f
#define COLLECT_T 0.93f
#define BSTAR_SAFE 3523       // bin >= 3523 -> lower edge 0.93005 > 0.93
#define CNT_STRIDE 32         // one 128B cache line per image counter
#define LBUF 1024             // per-block LDS candidate staging

// workspace layout (bytes)
static const size_t OFF_HIST  = 0;                                   // 32*4096*4 = 524288
static const size_t OFF_CNT   = 524288;                              // 32*128 = 4096
static const size_t OFF_BSTAR = OFF_CNT + 4096;                      // 128
static const size_t OFF_FLAG  = OFF_BSTAR + 128;                     // 128
static const size_t OFF_CAND  = OFF_FLAG + 128;                      // -> 528640; + 32*16384*8
static const size_t OFF_CBOX  = OFF_CAND + (size_t)NBI * CAPC * 8;
static const size_t OFF_CLS   = OFF_CBOX + (size_t)NBI * KCAND * 16;
static const size_t OFF_SCORE = OFF_CLS + (size_t)NBI * KCAND * 4;
static const size_t OFF_OVER  = OFF_SCORE + (size_t)NBI * KCAND * 4;

// ---------- Kernel 1: scores -> histogram (s>0.5) + collect (s>0.93) ----------
__global__ void k1_hist_collect(const float* __restrict__ pred,
                                u32* __restrict__ hist, u32* __restrict__ cntp,
                                u64* __restrict__ cand) {
    int b = blockIdx.y;
    __shared__ u32 lh[NBINS];
    __shared__ u64 sbuf[LBUF];
    __shared__ u32 sn;
    __shared__ u32 sbase;
    for (int i = threadIdx.x; i < NBINS; i += blockDim.x) lh[i] = 0;
    if (threadIdx.x == 0) sn = 0;
    __syncthreads();
    const float* p = pred + (size_t)b * NPRED * 85;
    int stride = gridDim.x * blockDim.x;
    for (int e = blockIdx.x * blockDim.x + threadIdx.x; e < NELEM; e += stride) {
        u32 n = (u32)e / NCC;
        u32 c = (u32)e - n * NCC;
        float obj = p[n * 85 + 4];
        if (obj > HIST_LO) {              // cv < 1 so s > 0.5 requires obj > 0.5
            float cv = p[n * 85 + 5 + c];
            float s = obj * cv;
            if (s > HIST_LO) {
                int ib = (int)((s - HIST_LO) * HIST_SCALE);
                if (ib > NBINS - 1) ib = NBINS - 1;
                atomicAdd(&lh[ib], 1u);
                if (s > COLLECT_T) {
                    u64 key = ((u64)__float_as_uint(s) << 32) | (u32)(~(u32)e);
                    u32 pos = atomicAdd(&sn, 1u);
                    if (pos < LBUF) sbuf[pos] = key;
                    else {                // overflow path (rare): direct global
                        u32 g = atomicAdd(&cntp[b * CNT_STRIDE], 1u);
                        if (g < CAPC) cand[(size_t)b * CAPC + g] = key;
                    }
                }
            }
        }
    }
    __syncthreads();
    u32 nc = sn; if (nc > LBUF) nc = LBUF;
    if (threadIdx.x == 0) sbase = atomicAdd(&cntp[b * CNT_STRIDE], nc);
    __syncthreads();
    u32 base = sbase;
    for (u32 i = threadIdx.x; i < nc; i += blockDim.x) {
        u32 g = base + i;
        if (g < CAPC) cand[(size_t)b * CAPC + g] = sbuf[i];
    }
    u32* gh = hist + (size_t)b * NBINS;
    for (int i = threadIdx.x; i < NBINS; i += blockDim.x) {
        u32 v = lh[i];
        if (v) atomicAdd(&gh[i], v);
    }
}

// ---------- Kernel 2: find exact threshold bin b* per image ----------
__global__ void k2_threshold(const u32* __restrict__ hist, u32* __restrict__ cntp,
                             int* __restrict__ bstar, int* __restrict__ flag) {
    int b = blockIdx.x;
    const u32* gh = hist + (size_t)b * NBINS;
    __shared__ u32 csum[256];
    u32 s = 0;
    for (int i = 0; i < 16; ++i) s += gh[threadIdx.x * 16 + i];
    csum[threadIdx.x] = s;
    __syncthreads();
    if (threadIdx.x == 0) {
        int bs = -1;
        u32 acc = 0; int cc = -1; u32 accBefore = 0;
        for (int c = 255; c >= 0; --c) {
            if (acc + csum[c] >= KCAND) { cc = c; accBefore = acc; break; }
            acc += csum[c];
        }
        if (cc >= 0) {
            u32 a2 = accBefore;
            for (int bi = cc * 16 + 15; bi >= cc * 16; --bi) {
                a2 += gh[bi];
                if (a2 >= KCAND) { bs = bi; break; }
            }
        }
        bool needfb;
        if (bs < 0) needfb = true;
        else needfb = (bs < BSTAR_SAFE) || (cntp[b * CNT_STRIDE] > CAPC);
        bstar[b] = bs;
        flag[b] = needfb ? 1 : 0;
        if (needfb) cntp[b * CNT_STRIDE] = 0;   // fallback kernel re-collects
    }
}

// ---------- Kernel 3: fallback collect (normally a no-op) ----------
__global__ void k3_fallback(const float* __restrict__ pred, u32* __restrict__ cntp,
                            u64* __restrict__ cand, const int* __restrict__ bstar,
                            const int* __restrict__ flag) {
    int b = blockIdx.y;
    if (!flag[b]) return;
    int bs = bstar[b];
    const float* p = pred + (size_t)b * NPRED * 85;
    int stride = gridDim.x * blockDim.x;
    for (int e = blockIdx.x * blockDim.x + threadIdx.x; e < NELEM; e += stride) {
        u32 n = (u32)e / NCC;
        u32 c = (u32)e - n * NCC;
        float obj = p[n * 85 + 4];
        float cv  = p[n * 85 + 5 + c];
        float s = obj * cv;
        bool take;
        if (bs < 0) take = (s > CONF);
        else take = (s > HIST_LO) && ((int)((s - HIST_LO) * HIST_SCALE) >= bs);
        if (take) {
            u32 pos = atomicAdd(&cntp[b * CNT_STRIDE], 1u);
            if (pos < CAPC) {
                u32 sb = __float_as_uint(s);
                cand[(size_t)b * CAPC + pos] = ((u64)sb << 32) | (u32)(~(u32)e);
            }
        }
    }
}

// ---------- Kernel 4: filter by bin>=b*, bitonic sort, take top-2048, gather boxes ----------
__global__ __launch_bounds__(1024) void k4_sort_gather(
        const float* __restrict__ pred, const u32* __restrict__ cntp,
        const u64* __restrict__ cand, const int* __restrict__ bstar,
        float4* __restrict__ cbox, float* __restrict__ clsArr, float* __restrict__ scoreArr) {
    int b = blockIdx.x;
    __shared__ u64 keys[SORTN];
    __shared__ u32 lcnt;
    if (threadIdx.x == 0) lcnt = 0;
    for (int i = threadIdx.x; i < SORTN; i += 1024) keys[i] = 0ULL;
    __syncthreads();
    int bs = bstar[b];
    u32 m = cntp[b * CNT_STRIDE]; if (m > CAPC) m = CAPC;
    for (u32 t = threadIdx.x; t < m; t += 1024) {
        u64 key = cand[(size_t)b * CAPC + t];
        float s = __uint_as_float((u32)(key >> 32));
        bool acc = (bs < 0) || ((s > HIST_LO) && ((int)((s - HIST_LO) * HIST_SCALE) >= bs));
        if (acc) {
            u32 pos = atomicAdd(&lcnt, 1u);
            if (pos < SORTN) keys[pos] = key;
        }
    }
    __syncthreads();
    // bitonic sort, descending on (score_bits, ~idx)
    for (int k = 2; k <= SORTN; k <<= 1) {
        for (int j = k >> 1; j > 0; j >>= 1) {
            for (int i = threadIdx.x; i < SORTN; i += 1024) {
                int ixj = i ^ j;
                if (ixj > i) {
                    u64 a = keys[i], bb = keys[ixj];
                    bool up = (i & k) == 0;
                    bool sw = up ? (a < bb) : (a > bb);
                    if (sw) { keys[i] = bb; keys[ixj] = a; }
                }
            }
            __syncthreads();
        }
    }
    const float* p = pred + (size_t)b * NPRED * 85;
    for (int t = threadIdx.x; t < KCAND; t += 1024) {
        u64 key = keys[t];
        float s = __uint_as_float((u32)(key >> 32));
        float4 cb; float cf; float sv;
        if (s > CONF) {
            u32 idx = ~(u32)key;
            u32 n = idx / NCC; u32 c = idx - n * NCC;
            float x = p[n * 85 + 0], y = p[n * 85 + 1];
            float w = p[n * 85 + 2], h = p[n * 85 + 3];
            float hw = w * 0.5f, hh = h * 0.5f;
            cb = make_float4(x - hw, y - hh, x + hw, y + hh);
            cf = (float)c; sv = s;
        } else {
            cb = make_float4(0.f, 0.f, 0.f, 0.f); cf = 0.f; sv = -1.f;
        }
        cbox[(size_t)b * KCAND + t] = cb;
        clsArr[(size_t)b * KCAND + t] = cf;
        scoreArr[(size_t)b * KCAND + t] = sv;
    }
}

// ---------- Kernel 5: IoU adjacency (only j > i bits), offset boxes like reference ----------
__global__ __launch_bounds__(1024) void k5_iou(const float4* __restrict__ cbox,
                                               const float* __restrict__ clsArr,
                                               u64* __restrict__ over) {
    int blk = blockIdx.x;          // 32 img * 64 row-blocks
    int b = blk >> 6;
    int rowBase = (blk & 63) << 5; // 32 rows per block
    __shared__ float ox1[KCAND], oy1[KCAND], ox2[KCAND], oy2[KCAND], oar[KCAND];
    for (int j = threadIdx.x; j < KCAND; j += 1024) {
        float4 cb = cbox[(size_t)b * KCAND + j];
        float off = clsArr[(size_t)b * KCAND + j] * MAXWH;
        float a = cb.x + off, c = cb.y + off, d = cb.z + off, e = cb.w + off;
        ox1[j] = a; oy1[j] = c; ox2[j] = d; oy2[j] = e;
        oar[j] = (d - a) * (e - c);   // area from offset coords, same as reference
    }
    __syncthreads();
    int w = threadIdx.x & 31;
    int r = threadIdx.x >> 5;
    int i = rowBase + r;
    float ix1 = ox1[i], iy1 = oy1[i], ix2 = ox2[i], iy2 = oy2[i], iar = oar[i];
    u64 bits = 0;
    int j0 = w << 6;
    if (j0 + 63 > i) {
        for (int jb = 0; jb < 64; ++jb) {
            int jj = (jb + w) & 63;         // rotate to avoid 32-way LDS bank conflicts
            int j = j0 + jj;
            if (j > i) {
                float lx = fmaxf(ix1, ox1[j]);
                float ly = fmaxf(iy1, oy1[j]);
                float rx = fminf(ix2, ox2[j]);
                float ry = fminf(iy2, oy2[j]);
                float iw = rx - lx; if (iw < 0.f) iw = 0.f;
                float ih = ry - ly; if (ih < 0.f) ih = 0.f;
                float inter = iw * ih;
                float uni = iar + oar[j] - inter;
                float iou = inter / uni;     // NaN for degenerate -> comparison false
                if (iou > IOU_T) bits |= (1ULL << jj);
            }
        }
    }
    over[((size_t)b * KCAND + i) * 32 + w] = bits;
}

// ---------- Kernel 6: greedy suppression over set bits + write output ----------
__global__ __launch_bounds__(64) void k6_nms_out(const float4* __restrict__ cbox,
                                                 const float* __restrict__ clsArr,
                                                 const float* __restrict__ scoreArr,
                                                 const u64* __restrict__ over,
                                                 float* __restrict__ out) {
    int b = blockIdx.x;
    int lane = threadIdx.x;
    __shared__ u64 keep[32];
    __shared__ unsigned short outl[MAXDET];
    const float* sc = scoreArr + (size_t)b * KCAND;
    for (int k = 0; k < 32; ++k) {
        u64 m = __ballot(sc[k * 64 + lane] > CONF);
        if (lane == k) keep[k] = m;
    }
    __syncthreads();
    int outc = 0;
    const u64* ov = over + (size_t)b * KCAND * 32;
    for (int w = 0; w < 32 && outc < MAXDET; ++w) {
        u64 m = keep[w];
        while (m && outc < MAXDET) {
            int t = __builtin_ctzll(m);
            int i = (w << 6) + t;
            if (lane == 0) outl[outc] = (unsigned short)i;
            outc++;
            u64 row = (lane < 32) ? ov[(size_t)i * 32 + lane] : 0ULL;
            if (lane < 32) keep[lane] &= ~row;   // row has only j>i bits
            __syncthreads();
            m = (t == 63) ? 0ULL : (keep[w] & (~0ULL << (t + 1)));
        }
    }
    __syncthreads();
    float* ob = out + (size_t)b * MAXDET * 6;
    for (int slot = lane; slot < MAXDET; slot += 64) {
        float v0 = 0.f, v1 = 0.f, v2 = 0.f, v3 = 0.f, v4 = 0.f, v5 = 0.f;
        if (slot < outc) {
            int i = outl[slot];
            float4 cb = cbox[(size_t)b * KCAND + i];
            v0 = cb.x; v1 = cb.y; v2 = cb.z; v3 = cb.w;
            v4 = sc[i];
            v5 = clsArr[(size_t)b * KCAND + i];
        }
        ob[slot * 6 + 0] = v0; ob[slot * 6 + 1] = v1; ob[slot * 6 + 2] = v2;
        ob[slot * 6 + 3] = v3; ob[slot * 6 + 4] = v4; ob[slot * 6 + 5] = v5;
    }
}

extern "C" void kernel_launch(void* const* d_in, const int* in_sizes, int n_in,
                              void* d_out, int out_size, void* d_ws, size_t ws_size,
                              hipStream_t stream) {
    const float* pred = (const float*)d_in[0];
    float* out = (float*)d_out;
    uint8_t* ws = (uint8_t*)d_ws;

    u32* hist   = (u32*)(ws + OFF_HIST);
    u32* cntp   = (u32*)(ws + OFF_CNT);
    int* bstar  = (int*)(ws + OFF_BSTAR);
    int* flag   = (int*)(ws + OFF_FLAG);
    u64* cand   = (u64*)(ws + OFF_CAND);
    float4* cbox   = (float4*)(ws + OFF_CBOX);
    float* clsArr  = (float*)(ws + OFF_CLS);
    float* scoreArr= (float*)(ws + OFF_SCORE);
    u64* over   = (u64*)(ws + OFF_OVER);

    // zero hist + counters (rest is fully overwritten where read)
    hipMemsetAsync(ws, 0, OFF_CAND, stream);

    dim3 g1(252, NBI);
    k1_hist_collect<<<g1, 256, 0, stream>>>(pred, hist, cntp, cand);
    k2_threshold<<<NBI, 256, 0, stream>>>(hist, cntp, bstar, flag);
    k3_fallback<<<g1, 256, 0, stream>>>(pred, cntp, cand, bstar, flag);
    k4_sort_gather<<<NBI, 1024, 0, stream>>>(pred, cntp, cand, bstar, cbox, clsArr, scoreArr);
    k5_iou<<<NBI * 64, 1024, 0, stream>>>(cbox, clsArr, over);
    k6_nms_out<<<NBI, 64, 0, stream>>>(cbox, clsArr, scoreArr, over, out);
}

// Round 3
// 276.344 us; speedup vs baseline: 4.0779x; 1.6531x over previous
//
#include <hip/hip_runtime.h>
#include <stdint.h>

typedef unsigned long long u64;
typedef unsigned int u32;

#define NCC 80
#define NPRED 25200
#define NBI 32
#define NELEM (NPRED * NCC)   // 2016000
#define KCAND 2048
#define MAXDET 300
#define CONF 0.001f
#define IOU_T 0.6f
#define MAXWH 4096.0f
#define CAPC 16384
#define NBINS 4096
#define SORTN 4096
#define HIST_LO 0.5f
#define HIST_SCALE 8192.0f
#define COLLECT_T 0.946f      // E[count>T] ~ 3000 per image, ~17 sigma inside [2048,4096]
#define CNT_STRIDE 32         // one 128B cache line per image counter
#define LBUF 256              // per-block LDS candidate staging (expect ~12/block)
#define CHUNK 8000            // NELEM / 252

// workspace layout (bytes)
static const size_t OFF_HIST  = 0;                                   // 32*4096*4 = 524288 (fallback only)
static const size_t OFF_CNT   = 524288;                              // 32*128
static const size_t OFF_BSTAR = OFF_CNT + 4096;
static const size_t OFF_FLAG  = OFF_BSTAR + 128;
static const size_t OFF_CAND  = OFF_FLAG + 128;                      // + 32*16384*8
static const size_t OFF_CBOX  = OFF_CAND + (size_t)NBI * CAPC * 8;
static const size_t OFF_CLS   = OFF_CBOX + (size_t)NBI * KCAND * 16;
static const size_t OFF_SCORE = OFF_CLS + (size_t)NBI * KCAND * 4;
static const size_t OFF_OVER  = OFF_SCORE + (size_t)NBI * KCAND * 4;

// ---------- Kernel 1: collect s > COLLECT_T only (no histogram) ----------
__global__ void k1_collect(const float* __restrict__ pred,
                           u32* __restrict__ cntp, u64* __restrict__ cand) {
    int b = blockIdx.y;
    __shared__ u64 sbuf[LBUF];
    __shared__ u32 sn, sbase;
    if (threadIdx.x == 0) sn = 0;
    __syncthreads();
    const float* p = pred + (size_t)b * NPRED * 85;
    int base = blockIdx.x * CHUNK;
    int end = base + CHUNK;
    for (int e = base + threadIdx.x; e < end; e += 256) {
        u32 n = (u32)e / NCC;
        u32 c = (u32)e - n * NCC;
        float obj = p[n * 85 + 4];
        if (obj > COLLECT_T) {            // cv < 1 so s > T requires obj > T
            float cv = p[n * 85 + 5 + c];
            float s = obj * cv;
            if (s > COLLECT_T) {
                u64 key = ((u64)__float_as_uint(s) << 32) | (u32)(~(u32)e);
                u32 pos = atomicAdd(&sn, 1u);
                if (pos < LBUF) sbuf[pos] = key;
                else {                    // overflow (rare): direct global
                    u32 g = atomicAdd(&cntp[b * CNT_STRIDE], 1u);
                    if (g < CAPC) cand[(size_t)b * CAPC + g] = key;
                }
            }
        }
    }
    __syncthreads();
    u32 nc = sn; if (nc > LBUF) nc = LBUF;
    if (threadIdx.x == 0) sbase = atomicAdd(&cntp[b * CNT_STRIDE], nc);
    __syncthreads();
    u32 bgn = sbase;
    for (u32 i = threadIdx.x; i < nc; i += 256) {
        u32 g = bgn + i;
        if (g < CAPC) cand[(size_t)b * CAPC + g] = sbuf[i];
    }
}

// ---------- Kernel 2: validity check; flag -> fallback path ----------
__global__ void k2_check(u32* __restrict__ cntp, int* __restrict__ flag) {
    int b = threadIdx.x;
    if (b < NBI) {
        u32 c = cntp[b * CNT_STRIDE];
        int f = (c < KCAND || c > SORTN) ? 1 : 0;
        flag[b] = f;
        if (f) cntp[b * CNT_STRIDE] = 0;   // fallback re-collects from scratch
    }
}

// ---------- Kernel 3a (fallback, flag-gated): full histogram ----------
__global__ void k3a_hist(const float* __restrict__ pred, u32* __restrict__ hist,
                         const int* __restrict__ flag) {
    int b = blockIdx.y;
    if (!flag[b]) return;
    __shared__ u32 lh[NBINS];
    for (int i = threadIdx.x; i < NBINS; i += blockDim.x) lh[i] = 0;
    __syncthreads();
    const float* p = pred + (size_t)b * NPRED * 85;
    int base = blockIdx.x * CHUNK;
    int end = base + CHUNK;
    for (int e = base + threadIdx.x; e < end; e += 256) {
        u32 n = (u32)e / NCC;
        u32 c = (u32)e - n * NCC;
        float obj = p[n * 85 + 4];
        if (obj > HIST_LO) {
            float cv = p[n * 85 + 5 + c];
            float s = obj * cv;
            if (s > HIST_LO) {
                int ib = (int)((s - HIST_LO) * HIST_SCALE);
                if (ib > NBINS - 1) ib = NBINS - 1;
                atomicAdd(&lh[ib], 1u);
            }
        }
    }
    __syncthreads();
    u32* gh = hist + (size_t)b * NBINS;
    for (int i = threadIdx.x; i < NBINS; i += blockDim.x) {
        u32 v = lh[i];
        if (v) atomicAdd(&gh[i], v);
    }
}

// ---------- Kernel 3b (fallback): exact threshold bin ----------
__global__ void k3b_thresh(const u32* __restrict__ hist, int* __restrict__ bstar,
                           const int* __restrict__ flag) {
    int b = blockIdx.x;
    if (!flag[b]) return;
    const u32* gh = hist + (size_t)b * NBINS;
    __shared__ u32 csum[256];
    u32 s = 0;
    for (int i = 0; i < 16; ++i) s += gh[threadIdx.x * 16 + i];
    csum[threadIdx.x] = s;
    __syncthreads();
    if (threadIdx.x == 0) {
        int bs = -1;
        u32 acc = 0; int cc = -1; u32 accBefore = 0;
        for (int c = 255; c >= 0; --c) {
            if (acc + csum[c] >= KCAND) { cc = c; accBefore = acc; break; }
            acc += csum[c];
        }
        if (cc >= 0) {
            u32 a2 = accBefore;
            for (int bi = cc * 16 + 15; bi >= cc * 16; --bi) {
                a2 += gh[bi];
                if (a2 >= KCAND) { bs = bi; break; }
            }
        }
        bstar[b] = bs;
    }
}

// ---------- Kernel 3c (fallback): re-collect by bin filter ----------
__global__ void k3c_collect(const float* __restrict__ pred, u32* __restrict__ cntp,
                            u64* __restrict__ cand, const int* __restrict__ bstar,
                            const int* __restrict__ flag) {
    int b = blockIdx.y;
    if (!flag[b]) return;
    int bs = bstar[b];
    const float* p = pred + (size_t)b * NPRED * 85;
    int base = blockIdx.x * CHUNK;
    int end = base + CHUNK;
    for (int e = base + threadIdx.x; e < end; e += 256) {
        u32 n = (u32)e / NCC;
        u32 c = (u32)e - n * NCC;
        float obj = p[n * 85 + 4];
        float cv  = p[n * 85 + 5 + c];
        float s = obj * cv;
        bool take;
        if (bs < 0) take = (s > CONF);
        else {
            int ib = (int)((s - HIST_LO) * HIST_SCALE);
            if (ib > NBINS - 1) ib = NBINS - 1;
            take = (s > HIST_LO) && (ib >= bs);
        }
        if (take) {
            u32 pos = atomicAdd(&cntp[b * CNT_STRIDE], 1u);
            if (pos < CAPC) {
                u32 sb = __float_as_uint(s);
                cand[(size_t)b * CAPC + pos] = ((u64)sb << 32) | (u32)(~(u32)e);
            }
        }
    }
}

// ---------- Kernel 4: copy keys, bitonic sort desc, top-2048, gather boxes ----------
__global__ __launch_bounds__(1024) void k4_sort_gather(
        const float* __restrict__ pred, const u32* __restrict__ cntp,
        const u64* __restrict__ cand,
        float4* __restrict__ cbox, float* __restrict__ clsArr, float* __restrict__ scoreArr) {
    int b = blockIdx.x;
    __shared__ u64 keys[SORTN];
    u32 m = cntp[b * CNT_STRIDE];
    if (m > SORTN) m = SORTN;   // only reachable in impossible fallback-overflow
    for (int i = threadIdx.x; i < SORTN; i += 1024)
        keys[i] = (i < (int)m) ? cand[(size_t)b * CAPC + i] : 0ULL;
    __syncthreads();
    for (int k = 2; k <= SORTN; k <<= 1) {
        for (int j = k >> 1; j > 0; j >>= 1) {
            for (int i = threadIdx.x; i < SORTN; i += 1024) {
                int ixj = i ^ j;
                if (ixj > i) {
                    u64 a = keys[i], bb = keys[ixj];
                    bool up = (i & k) == 0;
                    bool sw = up ? (a < bb) : (a > bb);
                    if (sw) { keys[i] = bb; keys[ixj] = a; }
                }
            }
            __syncthreads();
        }
    }
    const float* p = pred + (size_t)b * NPRED * 85;
    for (int t = threadIdx.x; t < KCAND; t += 1024) {
        u64 key = keys[t];
        float s = __uint_as_float((u32)(key >> 32));
        float4 cb; float cf; float sv;
        if (s > CONF) {
            u32 idx = ~(u32)key;
            u32 n = idx / NCC; u32 c = idx - n * NCC;
            float x = p[n * 85 + 0], y = p[n * 85 + 1];
            float w = p[n * 85 + 2], h = p[n * 85 + 3];
            float hw = w * 0.5f, hh = h * 0.5f;
            cb = make_float4(x - hw, y - hh, x + hw, y + hh);
            cf = (float)c; sv = s;
        } else {
            cb = make_float4(0.f, 0.f, 0.f, 0.f); cf = 0.f; sv = -1.f;
        }
        cbox[(size_t)b * KCAND + t] = cb;
        clsArr[(size_t)b * KCAND + t] = cf;
        scoreArr[(size_t)b * KCAND + t] = sv;
    }
}

// ---------- Kernel 5: IoU adjacency, class-match only (cross-class provably 0) ----------
__global__ __launch_bounds__(1024) void k5_iou(const float4* __restrict__ cbox,
                                               const float* __restrict__ clsArr,
                                               u64* __restrict__ over) {
    int blk = blockIdx.x;          // 32 img * 64 row-blocks
    int b = blk >> 6;
    int rowBase = (blk & 63) << 5; // 32 rows per block
    __shared__ float ox1[KCAND], oy1[KCAND], ox2[KCAND], oy2[KCAND], oar[KCAND], lcl[KCAND];
    for (int j = threadIdx.x; j < KCAND; j += 1024) {
        float4 cb = cbox[(size_t)b * KCAND + j];
        float cj = clsArr[(size_t)b * KCAND + j];
        ox1[j] = cb.x; oy1[j] = cb.y; ox2[j] = cb.z; oy2[j] = cb.w;
        oar[j] = (cb.z - cb.x) * (cb.w - cb.y);
        lcl[j] = cj;
    }
    __syncthreads();
    int w = threadIdx.x & 31;
    int r = threadIdx.x >> 5;
    int i = rowBase + r;
    float ci = lcl[i];
    float ix1 = ox1[i], iy1 = oy1[i], ix2 = ox2[i], iy2 = oy2[i], iar = oar[i];
    u64 bits = 0;
    int j0 = w << 6;
    for (int jb = 0; jb < 64; ++jb) {
        int jj = (jb + w) & 63;         // rotate to avoid LDS bank conflicts
        int j = j0 + jj;
        if (lcl[j] == ci) {             // same class only; backward/diag bits harmless
            float lx = fmaxf(ix1, ox1[j]);
            float ly = fmaxf(iy1, oy1[j]);
            float rx = fminf(ix2, ox2[j]);
            float ry = fminf(iy2, oy2[j]);
            float iw = rx - lx; if (iw < 0.f) iw = 0.f;
            float ih = ry - ly; if (ih < 0.f) ih = 0.f;
            float inter = iw * ih;
            float uni = iar + oar[j] - inter;
            float iou = inter / uni;     // NaN for degenerate -> false
            if (iou > IOU_T) bits |= (1ULL << jj);
        }
    }
    over[((size_t)b * KCAND + i) * 32 + w] = bits;
}

// ---------- Kernel 6: greedy suppression, chunked-LDS rows ----------
__global__ __launch_bounds__(64) void k6_nms_out(const float4* __restrict__ cbox,
                                                 const float* __restrict__ clsArr,
                                                 const float* __restrict__ scoreArr,
                                                 const u64* __restrict__ over,
                                                 float* __restrict__ out) {
    int b = blockIdx.x;
    int lane = threadIdx.x;
    __shared__ u64 keep[32];
    __shared__ u64 rowsf[64 * 32];       // 16 KB: one 64-candidate chunk of rows
    __shared__ unsigned short outl[MAXDET];
    const float* sc = scoreArr + (size_t)b * KCAND;
    for (int k = 0; k < 32; ++k) {
        u64 m = __ballot(sc[k * 64 + lane] > CONF);
        if (lane == k) keep[k] = m;
    }
    __syncthreads();
    int outc = 0;
    const u64* ov = over + (size_t)b * KCAND * 32;
    for (int w = 0; w < 32 && outc < MAXDET; ++w) {
        // coalesced load of this chunk's 64 rows (64*32 u64 = 16 KB)
        const u64* src = ov + (size_t)w * 64 * 32;
        for (int t = 0; t < 32; ++t) rowsf[lane + t * 64] = src[lane + t * 64];
        __syncthreads();
        u64 m = keep[w];
        while (m && outc < MAXDET) {
            int t = __builtin_ctzll(m);
            if (lane == 0) outl[outc] = (unsigned short)(w * 64 + t);
            outc++;
            if (lane < 32) keep[lane] &= ~rowsf[t * 32 + lane];
            __syncthreads();
            m = (t == 63) ? 0ULL : (keep[w] & (~0ULL << (t + 1)));
        }
        __syncthreads();
    }
    __syncthreads();
    float* ob = out + (size_t)b * MAXDET * 6;
    for (int slot = lane; slot < MAXDET; slot += 64) {
        float v0 = 0.f, v1 = 0.f, v2 = 0.f, v3 = 0.f, v4 = 0.f, v5 = 0.f;
        if (slot < outc) {
            int i = outl[slot];
            float4 cb = cbox[(size_t)b * KCAND + i];
            v0 = cb.x; v1 = cb.y; v2 = cb.z; v3 = cb.w;
            v4 = sc[i];
            v5 = clsArr[(size_t)b * KCAND + i];
        }
        ob[slot * 6 + 0] = v0; ob[slot * 6 + 1] = v1; ob[slot * 6 + 2] = v2;
        ob[slot * 6 + 3] = v3; ob[slot * 6 + 4] = v4; ob[slot * 6 + 5] = v5;
    }
}

extern "C" void kernel_launch(void* const* d_in, const int* in_sizes, int n_in,
                              void* d_out, int out_size, void* d_ws, size_t ws_size,
                              hipStream_t stream) {
    const float* pred = (const float*)d_in[0];
    float* out = (float*)d_out;
    uint8_t* ws = (uint8_t*)d_ws;

    u32* hist   = (u32*)(ws + OFF_HIST);
    u32* cntp   = (u32*)(ws + OFF_CNT);
    int* bstar  = (int*)(ws + OFF_BSTAR);
    int* flag   = (int*)(ws + OFF_FLAG);
    u64* cand   = (u64*)(ws + OFF_CAND);
    float4* cbox    = (float4*)(ws + OFF_CBOX);
    float* clsArr   = (float*)(ws + OFF_CLS);
    float* scoreArr = (float*)(ws + OFF_SCORE);
    u64* over   = (u64*)(ws + OFF_OVER);

    // zero hist (fallback) + counters + flags
    hipMemsetAsync(ws, 0, OFF_CAND, stream);

    dim3 g1(252, NBI);
    k1_collect<<<g1, 256, 0, stream>>>(pred, cntp, cand);
    k2_check<<<1, 64, 0, stream>>>(cntp, flag);
    k3a_hist<<<g1, 256, 0, stream>>>(pred, hist, flag);
    k3b_thresh<<<NBI, 256, 0, stream>>>(hist, bstar, flag);
    k3c_collect<<<g1, 256, 0, stream>>>(pred, cntp, cand, bstar, flag);
    k4_sort_gather<<<NBI, 1024, 0, stream>>>(pred, cntp, cand, cbox, clsArr, scoreArr);
    k5_iou<<<NBI * 64, 1024, 0, stream>>>(cbox, clsArr, over);
    k6_nms_out<<<NBI, 64, 0, stream>>>(cbox, clsArr, scoreArr, over, out);
}

// Round 4
// 275.809 us; speedup vs baseline: 4.0858x; 1.0019x over previous
//
#include <hip/hip_runtime.h>
#include <stdint.h>

typedef unsigned long long u64;
typedef unsigned int u32;

#define NCC 80
#define NPRED 25200
#define NBI 32
#define NELEM (NPRED * NCC)   // 2016000
#define KCAND 2048
#define MAXDET 300
#define CONF 0.001f
#define IOU_T 0.6f
#define MAXWH 4096.0f
#define CAPC 16384
#define NBINS 4096
#define SORTN 4096
#define HIST_LO 0.5f
#define HIST_SCALE 8192.0f
#define COLLECT_T 0.946f      // E[count>T] ~ 2985 per image, ~17 sigma inside [2048,4096]
#define CNT_STRIDE 32         // one 128B cache line per image counter
#define LBUF 256              // per-block LDS candidate staging (expect ~12/block)
#define CHUNK 8000            // NELEM / 252

// workspace layout (bytes)
static const size_t OFF_HIST  = 0;                                   // 32*4096*4 = 524288 (fallback only)
static const size_t OFF_CNT   = 524288;                              // 32*128
static const size_t OFF_BSTAR = OFF_CNT + 4096;
static const size_t OFF_FLAG  = OFF_BSTAR + 128;
static const size_t OFF_CAND  = OFF_FLAG + 128;                      // = 528640; + 32*16384*8
static const size_t OFF_CBOX  = OFF_CAND + (size_t)NBI * CAPC * 8;
static const size_t OFF_CLS   = OFF_CBOX + (size_t)NBI * KCAND * 16;
static const size_t OFF_SCORE = OFF_CLS + (size_t)NBI * KCAND * 4;
static const size_t OFF_OVER  = OFF_SCORE + (size_t)NBI * KCAND * 4;

#define INIT_U4 (OFF_CAND / 16)   // 33040 uint4 words to zero

// ---------- Kernel 0: zero hist+cnt+flags (replaces pathologically slow rocclr fill) ----------
__global__ void k0_init(uint4* __restrict__ ws4) {
    uint4 z = make_uint4(0u, 0u, 0u, 0u);
    int stride = gridDim.x * blockDim.x;
    for (int i = blockIdx.x * blockDim.x + threadIdx.x; i < INIT_U4; i += stride)
        ws4[i] = z;
}

// ---------- Kernel 1: collect s > COLLECT_T only (no histogram) ----------
__global__ void k1_collect(const float* __restrict__ pred,
                           u32* __restrict__ cntp, u64* __restrict__ cand) {
    int b = blockIdx.y;
    __shared__ u64 sbuf[LBUF];
    __shared__ u32 sn, sbase;
    if (threadIdx.x == 0) sn = 0;
    __syncthreads();
    const float* p = pred + (size_t)b * NPRED * 85;
    int base = blockIdx.x * CHUNK;
    int end = base + CHUNK;
    for (int e = base + threadIdx.x; e < end; e += 256) {
        u32 n = (u32)e / NCC;
        u32 c = (u32)e - n * NCC;
        float obj = p[n * 85 + 4];
        if (obj > COLLECT_T) {            // cv < 1 so s > T requires obj > T
            float cv = p[n * 85 + 5 + c];
            float s = obj * cv;
            if (s > COLLECT_T) {
                u64 key = ((u64)__float_as_uint(s) << 32) | (u32)(~(u32)e);
                u32 pos = atomicAdd(&sn, 1u);
                if (pos < LBUF) sbuf[pos] = key;
                else {                    // overflow (rare): direct global
                    u32 g = atomicAdd(&cntp[b * CNT_STRIDE], 1u);
                    if (g < CAPC) cand[(size_t)b * CAPC + g] = key;
                }
            }
        }
    }
    __syncthreads();
    u32 nc = sn; if (nc > LBUF) nc = LBUF;
    if (threadIdx.x == 0) sbase = atomicAdd(&cntp[b * CNT_STRIDE], nc);
    __syncthreads();
    u32 bgn = sbase;
    for (u32 i = threadIdx.x; i < nc; i += 256) {
        u32 g = bgn + i;
        if (g < CAPC) cand[(size_t)b * CAPC + g] = sbuf[i];
    }
}

// ---------- Kernel 2: validity check; flag -> fallback path ----------
__global__ void k2_check(u32* __restrict__ cntp, int* __restrict__ flag) {
    int b = threadIdx.x;
    if (b < NBI) {
        u32 c = cntp[b * CNT_STRIDE];
        int f = (c < KCAND || c > SORTN) ? 1 : 0;
        flag[b] = f;
        if (f) cntp[b * CNT_STRIDE] = 0;   // fallback re-collects from scratch
    }
}

// ---------- Kernel 3a (fallback, flag-gated): full histogram ----------
__global__ void k3a_hist(const float* __restrict__ pred, u32* __restrict__ hist,
                         const int* __restrict__ flag) {
    int b = blockIdx.y;
    if (!flag[b]) return;
    __shared__ u32 lh[NBINS];
    for (int i = threadIdx.x; i < NBINS; i += blockDim.x) lh[i] = 0;
    __syncthreads();
    const float* p = pred + (size_t)b * NPRED * 85;
    int base = blockIdx.x * CHUNK;
    int end = base + CHUNK;
    for (int e = base + threadIdx.x; e < end; e += 256) {
        u32 n = (u32)e / NCC;
        u32 c = (u32)e - n * NCC;
        float obj = p[n * 85 + 4];
        if (obj > HIST_LO) {
            float cv = p[n * 85 + 5 + c];
            float s = obj * cv;
            if (s > HIST_LO) {
                int ib = (int)((s - HIST_LO) * HIST_SCALE);
                if (ib > NBINS - 1) ib = NBINS - 1;
                atomicAdd(&lh[ib], 1u);
            }
        }
    }
    __syncthreads();
    u32* gh = hist + (size_t)b * NBINS;
    for (int i = threadIdx.x; i < NBINS; i += blockDim.x) {
        u32 v = lh[i];
        if (v) atomicAdd(&gh[i], v);
    }
}

// ---------- Kernel 3b (fallback): exact threshold bin ----------
__global__ void k3b_thresh(const u32* __restrict__ hist, int* __restrict__ bstar,
                           const int* __restrict__ flag) {
    int b = blockIdx.x;
    if (!flag[b]) return;
    const u32* gh = hist + (size_t)b * NBINS;
    __shared__ u32 csum[256];
    u32 s = 0;
    for (int i = 0; i < 16; ++i) s += gh[threadIdx.x * 16 + i];
    csum[threadIdx.x] = s;
    __syncthreads();
    if (threadIdx.x == 0) {
        int bs = -1;
        u32 acc = 0; int cc = -1; u32 accBefore = 0;
        for (int c = 255; c >= 0; --c) {
            if (acc + csum[c] >= KCAND) { cc = c; accBefore = acc; break; }
            acc += csum[c];
        }
        if (cc >= 0) {
            u32 a2 = accBefore;
            for (int bi = cc * 16 + 15; bi >= cc * 16; --bi) {
                a2 += gh[bi];
                if (a2 >= KCAND) { bs = bi; break; }
            }
        }
        bstar[b] = bs;
    }
}

// ---------- Kernel 3c (fallback): re-collect by bin filter ----------
__global__ void k3c_collect(const float* __restrict__ pred, u32* __restrict__ cntp,
                            u64* __restrict__ cand, const int* __restrict__ bstar,
                            const int* __restrict__ flag) {
    int b = blockIdx.y;
    if (!flag[b]) return;
    int bs = bstar[b];
    const float* p = pred + (size_t)b * NPRED * 85;
    int base = blockIdx.x * CHUNK;
    int end = base + CHUNK;
    for (int e = base + threadIdx.x; e < end; e += 256) {
        u32 n = (u32)e / NCC;
        u32 c = (u32)e - n * NCC;
        float obj = p[n * 85 + 4];
        float cv  = p[n * 85 + 5 + c];
        float s = obj * cv;
        bool take;
        if (bs < 0) take = (s > CONF);
        else {
            int ib = (int)((s - HIST_LO) * HIST_SCALE);
            if (ib > NBINS - 1) ib = NBINS - 1;
            take = (s > HIST_LO) && (ib >= bs);
        }
        if (take) {
            u32 pos = atomicAdd(&cntp[b * CNT_STRIDE], 1u);
            if (pos < CAPC) {
                u32 sb = __float_as_uint(s);
                cand[(size_t)b * CAPC + pos] = ((u64)sb << 32) | (u32)(~(u32)e);
            }
        }
    }
}

// ---------- Kernel 4: copy keys, bitonic sort desc, top-2048, gather boxes ----------
__global__ __launch_bounds__(1024) void k4_sort_gather(
        const float* __restrict__ pred, const u32* __restrict__ cntp,
        const u64* __restrict__ cand,
        float4* __restrict__ cbox, float* __restrict__ clsArr, float* __restrict__ scoreArr) {
    int b = blockIdx.x;
    __shared__ u64 keys[SORTN];
    u32 m = cntp[b * CNT_STRIDE];
    if (m > SORTN) m = SORTN;   // only reachable in impossible fallback-overflow
    for (int i = threadIdx.x; i < SORTN; i += 1024)
        keys[i] = (i < (int)m) ? cand[(size_t)b * CAPC + i] : 0ULL;
    __syncthreads();
    for (int k = 2; k <= SORTN; k <<= 1) {
        for (int j = k >> 1; j > 0; j >>= 1) {
            for (int i = threadIdx.x; i < SORTN; i += 1024) {
                int ixj = i ^ j;
                if (ixj > i) {
                    u64 a = keys[i], bb = keys[ixj];
                    bool up = (i & k) == 0;
                    bool sw = up ? (a < bb) : (a > bb);
                    if (sw) { keys[i] = bb; keys[ixj] = a; }
                }
            }
            __syncthreads();
        }
    }
    const float* p = pred + (size_t)b * NPRED * 85;
    for (int t = threadIdx.x; t < KCAND; t += 1024) {
        u64 key = keys[t];
        float s = __uint_as_float((u32)(key >> 32));
        float4 cb; float cf; float sv;
        if (s > CONF) {
            u32 idx = ~(u32)key;
            u32 n = idx / NCC; u32 c = idx - n * NCC;
            float x = p[n * 85 + 0], y = p[n * 85 + 1];
            float w = p[n * 85 + 2], h = p[n * 85 + 3];
            float hw = w * 0.5f, hh = h * 0.5f;
            cb = make_float4(x - hw, y - hh, x + hw, y + hh);
            cf = (float)c; sv = s;
        } else {
            cb = make_float4(0.f, 0.f, 0.f, 0.f); cf = 0.f; sv = -1.f;
        }
        cbox[(size_t)b * KCAND + t] = cb;
        clsArr[(size_t)b * KCAND + t] = cf;
        scoreArr[(size_t)b * KCAND + t] = sv;
    }
}

// ---------- Kernel 5: IoU adjacency, class-match only (cross-class provably 0) ----------
__global__ __launch_bounds__(1024) void k5_iou(const float4* __restrict__ cbox,
                                               const float* __restrict__ clsArr,
                                               u64* __restrict__ over) {
    int blk = blockIdx.x;          // 32 img * 64 row-blocks
    int b = blk >> 6;
    int rowBase = (blk & 63) << 5; // 32 rows per block
    __shared__ float ox1[KCAND], oy1[KCAND], ox2[KCAND], oy2[KCAND], oar[KCAND], lcl[KCAND];
    for (int j = threadIdx.x; j < KCAND; j += 1024) {
        float4 cb = cbox[(size_t)b * KCAND + j];
        float cj = clsArr[(size_t)b * KCAND + j];
        ox1[j] = cb.x; oy1[j] = cb.y; ox2[j] = cb.z; oy2[j] = cb.w;
        oar[j] = (cb.z - cb.x) * (cb.w - cb.y);
        lcl[j] = cj;
    }
    __syncthreads();
    int w = threadIdx.x & 31;
    int r = threadIdx.x >> 5;
    int i = rowBase + r;
    float ci = lcl[i];
    float ix1 = ox1[i], iy1 = oy1[i], ix2 = ox2[i], iy2 = oy2[i], iar = oar[i];
    u64 bits = 0;
    int j0 = w << 6;
    for (int jb = 0; jb < 64; ++jb) {
        int jj = (jb + w) & 63;         // rotate to avoid LDS bank conflicts
        int j = j0 + jj;
        if (lcl[j] == ci) {             // same class only; backward/diag bits harmless
            float lx = fmaxf(ix1, ox1[j]);
            float ly = fmaxf(iy1, oy1[j]);
            float rx = fminf(ix2, ox2[j]);
            float ry = fminf(iy2, oy2[j]);
            float iw = rx - lx; if (iw < 0.f) iw = 0.f;
            float ih = ry - ly; if (ih < 0.f) ih = 0.f;
            float inter = iw * ih;
            float uni = iar + oar[j] - inter;
            float iou = inter / uni;     // NaN for degenerate -> false
            if (iou > IOU_T) bits |= (1ULL << jj);
        }
    }
    over[((size_t)b * KCAND + i) * 32 + w] = bits;
}

// ---------- Kernel 6: greedy suppression, chunked-LDS rows ----------
__global__ __launch_bounds__(64) void k6_nms_out(const float4* __restrict__ cbox,
                                                 const float* __restrict__ clsArr,
                                                 const float* __restrict__ scoreArr,
                                                 const u64* __restrict__ over,
                                                 float* __restrict__ out) {
    int b = blockIdx.x;
    int lane = threadIdx.x;
    __shared__ u64 keep[32];
    __shared__ u64 rowsf[64 * 32];       // 16 KB: one 64-candidate chunk of rows
    __shared__ unsigned short outl[MAXDET];
    const float* sc = scoreArr + (size_t)b * KCAND;
    for (int k = 0; k < 32; ++k) {
        u64 m = __ballot(sc[k * 64 + lane] > CONF);
        if (lane == k) keep[k] = m;
    }
    __syncthreads();
    int outc = 0;
    const u64* ov = over + (size_t)b * KCAND * 32;
    for (int w = 0; w < 32 && outc < MAXDET; ++w) {
        // coalesced load of this chunk's 64 rows (64*32 u64 = 16 KB)
        const u64* src = ov + (size_t)w * 64 * 32;
        for (int t = 0; t < 32; ++t) rowsf[lane + t * 64] = src[lane + t * 64];
        __syncthreads();
        u64 m = keep[w];
        while (m && outc < MAXDET) {
            int t = __builtin_ctzll(m);
            if (lane == 0) outl[outc] = (unsigned short)(w * 64 + t);
            outc++;
            if (lane < 32) keep[lane] &= ~rowsf[t * 32 + lane];
            __syncthreads();
            m = (t == 63) ? 0ULL : (keep[w] & (~0ULL << (t + 1)));
        }
        __syncthreads();
    }
    __syncthreads();
    float* ob = out + (size_t)b * MAXDET * 6;
    for (int slot = lane; slot < MAXDET; slot += 64) {
        float v0 = 0.f, v1 = 0.f, v2 = 0.f, v3 = 0.f, v4 = 0.f, v5 = 0.f;
        if (slot < outc) {
            int i = outl[slot];
            float4 cb = cbox[(size_t)b * KCAND + i];
            v0 = cb.x; v1 = cb.y; v2 = cb.z; v3 = cb.w;
            v4 = sc[i];
            v5 = clsArr[(size_t)b * KCAND + i];
        }
        ob[slot * 6 + 0] = v0; ob[slot * 6 + 1] = v1; ob[slot * 6 + 2] = v2;
        ob[slot * 6 + 3] = v3; ob[slot * 6 + 4] = v4; ob[slot * 6 + 5] = v5;
    }
}

extern "C" void kernel_launch(void* const* d_in, const int* in_sizes, int n_in,
                              void* d_out, int out_size, void* d_ws, size_t ws_size,
                              hipStream_t stream) {
    const float* pred = (const float*)d_in[0];
    float* out = (float*)d_out;
    uint8_t* ws = (uint8_t*)d_ws;

    u32* hist   = (u32*)(ws + OFF_HIST);
    u32* cntp   = (u32*)(ws + OFF_CNT);
    int* bstar  = (int*)(ws + OFF_BSTAR);
    int* flag   = (int*)(ws + OFF_FLAG);
    u64* cand   = (u64*)(ws + OFF_CAND);
    float4* cbox    = (float4*)(ws + OFF_CBOX);
    float* clsArr   = (float*)(ws + OFF_CLS);
    float* scoreArr = (float*)(ws + OFF_SCORE);
    u64* over   = (u64*)(ws + OFF_OVER);

    k0_init<<<130, 256, 0, stream>>>((uint4*)ws);

    dim3 g1(252, NBI);
    k1_collect<<<g1, 256, 0, stream>>>(pred, cntp, cand);
    k2_check<<<1, 64, 0, stream>>>(cntp, flag);
    k3a_hist<<<g1, 256, 0, stream>>>(pred, hist, flag);
    k3b_thresh<<<NBI, 256, 0, stream>>>(hist, bstar, flag);
    k3c_collect<<<g1, 256, 0, stream>>>(pred, cntp, cand, bstar, flag);
    k4_sort_gather<<<NBI, 1024, 0, stream>>>(pred, cntp, cand, cbox, clsArr, scoreArr);
    k5_iou<<<NBI * 64, 1024, 0, stream>>>(cbox, clsArr, over);
    k6_nms_out<<<NBI, 64, 0, stream>>>(cbox, clsArr, scoreArr, over, out);
}

// Round 5
// 274.421 us; speedup vs baseline: 4.1065x; 1.0051x over previous
//
#include <hip/hip_runtime.h>
#include <stdint.h>

typedef unsigned long long u64;
typedef unsigned int u32;

#define NCC 80
#define NPRED 25200
#define NBI 32
#define NELEM (NPRED * NCC)   // 2016000
#define KCAND 2048
#define MAXDET 300
#define CONF 0.001f
#define IOU_T 0.6f
#define MAXWH 4096.0f
#define CAPC 16384
#define NBINS 4096
#define SORTN 4096
#define HIST_LO 0.5f
#define HIST_SCALE 8192.0f
#define COLLECT_T 0.946f      // E[count>T] ~ 2988 per image, ~17 sigma inside [2048,4096]
#define CNT_STRIDE 32         // one 128B cache line per image counter
#define LBUF 256              // per-block LDS candidate staging (expect ~12/block)
#define CHUNK 8000            // NELEM / 252

// workspace layout (bytes)
static const size_t OFF_HIST  = 0;                                   // 32*4096*4 = 524288 (fallback only, NOT pre-zeroed)
static const size_t OFF_CNT   = 524288;                              // 32*128
static const size_t OFF_BSTAR = OFF_CNT + 4096;
static const size_t OFF_FLAG  = OFF_BSTAR + 128;
static const size_t OFF_CAND  = OFF_FLAG + 128;                      // = 528640; + 32*16384*8
static const size_t OFF_CBOX  = OFF_CAND + (size_t)NBI * CAPC * 8;
static const size_t OFF_CLS   = OFF_CBOX + (size_t)NBI * KCAND * 16;
static const size_t OFF_SCORE = OFF_CLS + (size_t)NBI * KCAND * 4;
static const size_t OFF_OVER  = OFF_SCORE + (size_t)NBI * KCAND * 4;

#define INIT_U32 ((4096 + 128 + 128) / 4)   // 1088 u32: cnt + bstar + flag ONLY (4.3 KB)

// ---------- Kernel 0: zero cnt/bstar/flag only (tiny write; survives fill starvation) ----------
__global__ void k0_init(u32* __restrict__ cntregion) {
    int i = blockIdx.x * blockDim.x + threadIdx.x;
    if (i < INIT_U32) cntregion[i] = 0;
}

// ---------- Kernel 1: collect s > COLLECT_T only (no histogram) ----------
__global__ void k1_collect(const float* __restrict__ pred,
                           u32* __restrict__ cntp, u64* __restrict__ cand) {
    int b = blockIdx.y;
    __shared__ u64 sbuf[LBUF];
    __shared__ u32 sn, sbase;
    if (threadIdx.x == 0) sn = 0;
    __syncthreads();
    const float* p = pred + (size_t)b * NPRED * 85;
    int base = blockIdx.x * CHUNK;
    int end = base + CHUNK;
    for (int e = base + threadIdx.x; e < end; e += 256) {
        u32 n = (u32)e / NCC;
        u32 c = (u32)e - n * NCC;
        float obj = p[n * 85 + 4];
        if (obj > COLLECT_T) {            // cv < 1 so s > T requires obj > T
            float cv = p[n * 85 + 5 + c];
            float s = obj * cv;
            if (s > COLLECT_T) {
                u64 key = ((u64)__float_as_uint(s) << 32) | (u32)(~(u32)e);
                u32 pos = atomicAdd(&sn, 1u);
                if (pos < LBUF) sbuf[pos] = key;
                else {                    // overflow (rare): direct global
                    u32 g = atomicAdd(&cntp[b * CNT_STRIDE], 1u);
                    if (g < CAPC) cand[(size_t)b * CAPC + g] = key;
                }
            }
        }
    }
    __syncthreads();
    u32 nc = sn; if (nc > LBUF) nc = LBUF;
    if (threadIdx.x == 0) sbase = atomicAdd(&cntp[b * CNT_STRIDE], nc);
    __syncthreads();
    u32 bgn = sbase;
    for (u32 i = threadIdx.x; i < nc; i += 256) {
        u32 g = bgn + i;
        if (g < CAPC) cand[(size_t)b * CAPC + g] = sbuf[i];
    }
}

// ---------- Kernel 2: validity check; flag -> fallback path ----------
__global__ void k2_check(u32* __restrict__ cntp, int* __restrict__ flag) {
    int b = threadIdx.x;
    if (b < NBI) {
        u32 c = cntp[b * CNT_STRIDE];
        int f = (c < KCAND || c > SORTN) ? 1 : 0;
        flag[b] = f;
        if (f) cntp[b * CNT_STRIDE] = 0;   // fallback re-collects from scratch
    }
}

// ---------- Kernel 3a (fallback, flag-gated): one block per image, full hist WRITE ----------
__global__ __launch_bounds__(1024) void k3a_hist(const float* __restrict__ pred,
                                                 u32* __restrict__ hist,
                                                 const int* __restrict__ flag) {
    int b = blockIdx.x;
    if (!flag[b]) return;
    __shared__ u32 lh[NBINS];
    for (int i = threadIdx.x; i < NBINS; i += 1024) lh[i] = 0;
    __syncthreads();
    const float* p = pred + (size_t)b * NPRED * 85;
    for (int e = threadIdx.x; e < NELEM; e += 1024) {
        u32 n = (u32)e / NCC;
        u32 c = (u32)e - n * NCC;
        float obj = p[n * 85 + 4];
        if (obj > HIST_LO) {
            float cv = p[n * 85 + 5 + c];
            float s = obj * cv;
            if (s > HIST_LO) {
                int ib = (int)((s - HIST_LO) * HIST_SCALE);
                if (ib > NBINS - 1) ib = NBINS - 1;
                atomicAdd(&lh[ib], 1u);
            }
        }
    }
    __syncthreads();
    u32* gh = hist + (size_t)b * NBINS;
    for (int i = threadIdx.x; i < NBINS; i += 1024) gh[i] = lh[i];  // plain write, no pre-zero needed
}

// ---------- Kernel 3b (fallback): exact threshold bin ----------
__global__ void k3b_thresh(const u32* __restrict__ hist, int* __restrict__ bstar,
                           const int* __restrict__ flag) {
    int b = blockIdx.x;
    if (!flag[b]) return;
    const u32* gh = hist + (size_t)b * NBINS;
    __shared__ u32 csum[256];
    u32 s = 0;
    for (int i = 0; i < 16; ++i) s += gh[threadIdx.x * 16 + i];
    csum[threadIdx.x] = s;
    __syncthreads();
    if (threadIdx.x == 0) {
        int bs = -1;
        u32 acc = 0; int cc = -1; u32 accBefore = 0;
        for (int c = 255; c >= 0; --c) {
            if (acc + csum[c] >= KCAND) { cc = c; accBefore = acc; break; }
            acc += csum[c];
        }
        if (cc >= 0) {
            u32 a2 = accBefore;
            for (int bi = cc * 16 + 15; bi >= cc * 16; --bi) {
                a2 += gh[bi];
                if (a2 >= KCAND) { bs = bi; break; }
            }
        }
        bstar[b] = bs;
    }
}

// ---------- Kernel 3c (fallback): re-collect by bin filter ----------
__global__ void k3c_collect(const float* __restrict__ pred, u32* __restrict__ cntp,
                            u64* __restrict__ cand, const int* __restrict__ bstar,
                            const int* __restrict__ flag) {
    int b = blockIdx.y;
    if (!flag[b]) return;
    int bs = bstar[b];
    const float* p = pred + (size_t)b * NPRED * 85;
    int base = blockIdx.x * CHUNK;
    int end = base + CHUNK;
    for (int e = base + threadIdx.x; e < end; e += 256) {
        u32 n = (u32)e / NCC;
        u32 c = (u32)e - n * NCC;
        float obj = p[n * 85 + 4];
        float cv  = p[n * 85 + 5 + c];
        float s = obj * cv;
        bool take;
        if (bs < 0) take = (s > CONF);
        else {
            int ib = (int)((s - HIST_LO) * HIST_SCALE);
            if (ib > NBINS - 1) ib = NBINS - 1;
            take = (s > HIST_LO) && (ib >= bs);
        }
        if (take) {
            u32 pos = atomicAdd(&cntp[b * CNT_STRIDE], 1u);
            if (pos < CAPC) {
                u32 sb = __float_as_uint(s);
                cand[(size_t)b * CAPC + pos] = ((u64)sb << 32) | (u32)(~(u32)e);
            }
        }
    }
}

// ---------- Kernel 4: copy keys, bitonic sort desc, top-2048, gather boxes ----------
__global__ __launch_bounds__(1024) void k4_sort_gather(
        const float* __restrict__ pred, const u32* __restrict__ cntp,
        const u64* __restrict__ cand,
        float4* __restrict__ cbox, float* __restrict__ clsArr, float* __restrict__ scoreArr) {
    int b = blockIdx.x;
    __shared__ u64 keys[SORTN];
    u32 m = cntp[b * CNT_STRIDE];
    if (m > SORTN) m = SORTN;
    for (int i = threadIdx.x; i < SORTN; i += 1024)
        keys[i] = (i < (int)m) ? cand[(size_t)b * CAPC + i] : 0ULL;
    __syncthreads();
    for (int k = 2; k <= SORTN; k <<= 1) {
        for (int j = k >> 1; j > 0; j >>= 1) {
            for (int i = threadIdx.x; i < SORTN; i += 1024) {
                int ixj = i ^ j;
                if (ixj > i) {
                    u64 a = keys[i], bb = keys[ixj];
                    bool up = (i & k) == 0;
                    bool sw = up ? (a < bb) : (a > bb);
                    if (sw) { keys[i] = bb; keys[ixj] = a; }
                }
            }
            __syncthreads();
        }
    }
    const float* p = pred + (size_t)b * NPRED * 85;
    for (int t = threadIdx.x; t < KCAND; t += 1024) {
        u64 key = keys[t];
        float s = __uint_as_float((u32)(key >> 32));
        float4 cb; float cf; float sv;
        if (s > CONF) {
            u32 idx = ~(u32)key;
            u32 n = idx / NCC; u32 c = idx - n * NCC;
            float x = p[n * 85 + 0], y = p[n * 85 + 1];
            float w = p[n * 85 + 2], h = p[n * 85 + 3];
            float hw = w * 0.5f, hh = h * 0.5f;
            cb = make_float4(x - hw, y - hh, x + hw, y + hh);
            cf = (float)c; sv = s;
        } else {
            cb = make_float4(0.f, 0.f, 0.f, 0.f); cf = 0.f; sv = -1.f;
        }
        cbox[(size_t)b * KCAND + t] = cb;
        clsArr[(size_t)b * KCAND + t] = cf;
        scoreArr[(size_t)b * KCAND + t] = sv;
    }
}

// ---------- Kernel 5: IoU adjacency, class-match only (cross-class provably 0) ----------
__global__ __launch_bounds__(1024) void k5_iou(const float4* __restrict__ cbox,
                                               const float* __restrict__ clsArr,
                                               u64* __restrict__ over) {
    int blk = blockIdx.x;          // 32 img * 64 row-blocks
    int b = blk >> 6;
    int rowBase = (blk & 63) << 5; // 32 rows per block
    __shared__ float ox1[KCAND], oy1[KCAND], ox2[KCAND], oy2[KCAND], oar[KCAND], lcl[KCAND];
    for (int j = threadIdx.x; j < KCAND; j += 1024) {
        float4 cb = cbox[(size_t)b * KCAND + j];
        float cj = clsArr[(size_t)b * KCAND + j];
        ox1[j] = cb.x; oy1[j] = cb.y; ox2[j] = cb.z; oy2[j] = cb.w;
        oar[j] = (cb.z - cb.x) * (cb.w - cb.y);
        lcl[j] = cj;
    }
    __syncthreads();
    int w = threadIdx.x & 31;
    int r = threadIdx.x >> 5;
    int i = rowBase + r;
    float ci = lcl[i];
    float ix1 = ox1[i], iy1 = oy1[i], ix2 = ox2[i], iy2 = oy2[i], iar = oar[i];
    u64 bits = 0;
    int j0 = w << 6;
    for (int jb = 0; jb < 64; ++jb) {
        int jj = (jb + w) & 63;         // rotate to avoid LDS bank conflicts
        int j = j0 + jj;
        if (lcl[j] == ci) {             // same class only; backward/diag bits harmless
            float lx = fmaxf(ix1, ox1[j]);
            float ly = fmaxf(iy1, oy1[j]);
            float rx = fminf(ix2, ox2[j]);
            float ry = fminf(iy2, oy2[j]);
            float iw = rx - lx; if (iw < 0.f) iw = 0.f;
            float ih = ry - ly; if (ih < 0.f) ih = 0.f;
            float inter = iw * ih;
            float uni = iar + oar[j] - inter;
            float iou = inter / uni;     // NaN for degenerate -> false
            if (iou > IOU_T) bits |= (1ULL << jj);
        }
    }
    over[((size_t)b * KCAND + i) * 32 + w] = bits;
}

// ---------- Kernel 6: greedy suppression, chunked-LDS rows ----------
__global__ __launch_bounds__(64) void k6_nms_out(const float4* __restrict__ cbox,
                                                 const float* __restrict__ clsArr,
                                                 const float* __restrict__ scoreArr,
                                                 const u64* __restrict__ over,
                                                 float* __restrict__ out) {
    int b = blockIdx.x;
    int lane = threadIdx.x;
    __shared__ u64 keep[32];
    __shared__ u64 rowsf[64 * 32];       // 16 KB: one 64-candidate chunk of rows
    __shared__ unsigned short outl[MAXDET];
    const float* sc = scoreArr + (size_t)b * KCAND;
    for (int k = 0; k < 32; ++k) {
        u64 m = __ballot(sc[k * 64 + lane] > CONF);
        if (lane == k) keep[k] = m;
    }
    __syncthreads();
    int outc = 0;
    const u64* ov = over + (size_t)b * KCAND * 32;
    for (int w = 0; w < 32 && outc < MAXDET; ++w) {
        const u64* src = ov + (size_t)w * 64 * 32;
        for (int t = 0; t < 32; ++t) rowsf[lane + t * 64] = src[lane + t * 64];
        __syncthreads();
        u64 m = keep[w];
        while (m && outc < MAXDET) {
            int t = __builtin_ctzll(m);
            if (lane == 0) outl[outc] = (unsigned short)(w * 64 + t);
            outc++;
            if (lane < 32) keep[lane] &= ~rowsf[t * 32 + lane];
            __syncthreads();
            m = (t == 63) ? 0ULL : (keep[w] & (~0ULL << (t + 1)));
        }
        __syncthreads();
    }
    __syncthreads();
    float* ob = out + (size_t)b * MAXDET * 6;
    for (int slot = lane; slot < MAXDET; slot += 64) {
        float v0 = 0.f, v1 = 0.f, v2 = 0.f, v3 = 0.f, v4 = 0.f, v5 = 0.f;
        if (slot < outc) {
            int i = outl[slot];
            float4 cb = cbox[(size_t)b * KCAND + i];
            v0 = cb.x; v1 = cb.y; v2 = cb.z; v3 = cb.w;
            v4 = sc[i];
            v5 = clsArr[(size_t)b * KCAND + i];
        }
        ob[slot * 6 + 0] = v0; ob[slot * 6 + 1] = v1; ob[slot * 6 + 2] = v2;
        ob[slot * 6 + 3] = v3; ob[slot * 6 + 4] = v4; ob[slot * 6 + 5] = v5;
    }
}

extern "C" void kernel_launch(void* const* d_in, const int* in_sizes, int n_in,
                              void* d_out, int out_size, void* d_ws, size_t ws_size,
                              hipStream_t stream) {
    const float* pred = (const float*)d_in[0];
    float* out = (float*)d_out;
    uint8_t* ws = (uint8_t*)d_ws;

    u32* hist   = (u32*)(ws + OFF_HIST);
    u32* cntp   = (u32*)(ws + OFF_CNT);
    int* bstar  = (int*)(ws + OFF_BSTAR);
    int* flag   = (int*)(ws + OFF_FLAG);
    u64* cand   = (u64*)(ws + OFF_CAND);
    float4* cbox    = (float4*)(ws + OFF_CBOX);
    float* clsArr   = (float*)(ws + OFF_CLS);
    float* scoreArr = (float*)(ws + OFF_SCORE);
    u64* over   = (u64*)(ws + OFF_OVER);

    k0_init<<<5, 256, 0, stream>>>((u32*)(ws + OFF_CNT));   // 4.3 KB only

    dim3 g1(252, NBI);
    k1_collect<<<g1, 256, 0, stream>>>(pred, cntp, cand);
    k2_check<<<1, 64, 0, stream>>>(cntp, flag);
    k3a_hist<<<NBI, 1024, 0, stream>>>(pred, hist, flag);
    k3b_thresh<<<NBI, 256, 0, stream>>>(hist, bstar, flag);
    k3c_collect<<<g1, 256, 0, stream>>>(pred, cntp, cand, bstar, flag);
    k4_sort_gather<<<NBI, 1024, 0, stream>>>(pred, cntp, cand, cbox, clsArr, scoreArr);
    k5_iou<<<NBI * 64, 1024, 0, stream>>>(cbox, clsArr, over);
    k6_nms_out<<<NBI, 64, 0, stream>>>(cbox, clsArr, scoreArr, over, out);
}

// Round 6
// 239.383 us; speedup vs baseline: 4.7075x; 1.1464x over previous
//
#include <hip/hip_runtime.h>
#include <stdint.h>

typedef unsigned long long u64;
typedef unsigned int u32;

#define NCC 80
#define NPRED 25200
#define NBI 32
#define NELEM (NPRED * NCC)   // 2016000
#define KCAND 2048
#define MAXDET 300
#define CONF 0.001f
#define IOU_T 0.6f
#define MAXWH 4096.0f
#define CAPC 16384
#define NBINS 4096
#define SORTN 4096
#define HIST_LO 0.5f
#define HIST_SCALE 8192.0f
#define COLLECT_T 0.946f      // E[count>T] ~ 2988 per image, ~17 sigma inside [2048,4096]
#define CNT_STRIDE 32         // one 128B cache line per image counter
#define LBUF 512              // per-block LDS candidate staging (expect ~30/block)
#define QMAX 256              // hot-row queue (<= rows per block)
#define ROWS_PER_BLK 256
#define K1_GX ((NPRED + ROWS_PER_BLK - 1) / ROWS_PER_BLK)   // 99
#define CHUNK 8000            // NELEM / 252 (fallback k3c only)

// workspace layout (bytes) — histogram eliminated (fallback hist lives in LDS)
static const size_t OFF_CNT   = 0;                                   // 32*128 = 4096
static const size_t OFF_BSTAR = 4096;                                // 128
static const size_t OFF_FLAG  = 4224;                                // 128
static const size_t OFF_CAND  = 4352;                                // + 32*16384*8
static const size_t OFF_CBOX  = OFF_CAND + (size_t)NBI * CAPC * 8;
static const size_t OFF_CLS   = OFF_CBOX + (size_t)NBI * KCAND * 16;
static const size_t OFF_SCORE = OFF_CLS + (size_t)NBI * KCAND * 4;
static const size_t OFF_OVER  = OFF_SCORE + (size_t)NBI * KCAND * 4;

#define INIT_U32 ((int)(OFF_CAND / 4))   // 1088 u32: cnt + bstar + flag (4.3 KB)

// ---------- Kernel 0: zero cnt/bstar/flag (tiny) ----------
__global__ void k0_init(u32* __restrict__ cntregion) {
    int i = blockIdx.x * blockDim.x + threadIdx.x;
    if (i < INIT_U32) cntregion[i] = 0;
}

// ---------- Kernel 1: row-scan + cooperative class-scan, collect s > COLLECT_T ----------
__global__ void k1_collect(const float* __restrict__ pred,
                           u32* __restrict__ cntp, u64* __restrict__ cand) {
    int b = blockIdx.y;
    __shared__ u32 hotrow[QMAX];
    __shared__ float hotobj[QMAX];
    __shared__ u64 sbuf[LBUF];
    __shared__ u32 hq, sn, sbase;
    if (threadIdx.x == 0) { hq = 0; sn = 0; }
    __syncthreads();
    const float* p = pred + (size_t)b * NPRED * 85;
    // phase 1: one obj load per row; queue hot rows (cv<1 so s>T requires obj>T)
    int row = blockIdx.x * ROWS_PER_BLK + threadIdx.x;
    if (row < NPRED) {
        float obj = p[row * 85 + 4];
        if (obj > COLLECT_T) {
            u32 q = atomicAdd(&hq, 1u);
            hotrow[q] = (u32)row; hotobj[q] = obj;
        }
    }
    __syncthreads();
    // phase 2: one wave per hot row; 64 lanes cover 80 classes in 2 strided slabs
    u32 nh = hq;
    int wid = threadIdx.x >> 6, lane = threadIdx.x & 63;
    for (u32 q = (u32)wid; q < nh; q += 4) {
        u32 r = hotrow[q]; float obj = hotobj[q];
        const float* rp = p + (size_t)r * 85 + 5;
        #pragma unroll
        for (int t = 0; t < 2; ++t) {
            int c = lane + t * 64;
            if (c < NCC) {
                float s = obj * rp[c];
                if (s > COLLECT_T) {
                    u64 key = ((u64)__float_as_uint(s) << 32) | (u32)(~(u32)(r * NCC + (u32)c));
                    u32 pos = atomicAdd(&sn, 1u);
                    if (pos < LBUF) sbuf[pos] = key;
                    else {                    // overflow (astronomically rare): direct global
                        u32 g = atomicAdd(&cntp[b * CNT_STRIDE], 1u);
                        if (g < CAPC) cand[(size_t)b * CAPC + g] = key;
                    }
                }
            }
        }
    }
    __syncthreads();
    u32 nc = sn; if (nc > LBUF) nc = LBUF;
    if (threadIdx.x == 0) sbase = atomicAdd(&cntp[b * CNT_STRIDE], nc);
    __syncthreads();
    u32 bgn = sbase;
    for (u32 i = threadIdx.x; i < nc; i += 256) {
        u32 g = bgn + i;
        if (g < CAPC) cand[(size_t)b * CAPC + g] = sbuf[i];
    }
}

// ---------- Kernel 2: validity check; flag -> fallback path ----------
__global__ void k2_check(u32* __restrict__ cntp, int* __restrict__ flag) {
    int b = threadIdx.x;
    if (b < NBI) {
        u32 c = cntp[b * CNT_STRIDE];
        int f = (c < KCAND || c > SORTN) ? 1 : 0;
        flag[b] = f;
        if (f) cntp[b * CNT_STRIDE] = 0;   // fallback re-collects from scratch
    }
}

// ---------- Kernel 3ab (fallback, flag-gated): LDS hist + exact threshold bin ----------
__global__ __launch_bounds__(1024) void k3ab_hist_thresh(const float* __restrict__ pred,
                                                         int* __restrict__ bstar,
                                                         const int* __restrict__ flag) {
    int b = blockIdx.x;
    if (!flag[b]) return;
    __shared__ u32 lh[NBINS];
    __shared__ u32 csum[256];
    for (int i = threadIdx.x; i < NBINS; i += 1024) lh[i] = 0;
    __syncthreads();
    const float* p = pred + (size_t)b * NPRED * 85;
    for (int e = threadIdx.x; e < NELEM; e += 1024) {
        u32 n = (u32)e / NCC;
        u32 c = (u32)e - n * NCC;
        float obj = p[n * 85 + 4];
        if (obj > HIST_LO) {
            float cv = p[n * 85 + 5 + c];
            float s = obj * cv;
            if (s > HIST_LO) {
                int ib = (int)((s - HIST_LO) * HIST_SCALE);
                if (ib > NBINS - 1) ib = NBINS - 1;
                atomicAdd(&lh[ib], 1u);
            }
        }
    }
    __syncthreads();
    if (threadIdx.x < 256) {
        u32 s = 0;
        for (int i = 0; i < 16; ++i) s += lh[threadIdx.x * 16 + i];
        csum[threadIdx.x] = s;
    }
    __syncthreads();
    if (threadIdx.x == 0) {
        int bs = -1;
        u32 acc = 0; int cc = -1; u32 accBefore = 0;
        for (int c = 255; c >= 0; --c) {
            if (acc + csum[c] >= KCAND) { cc = c; accBefore = acc; break; }
            acc += csum[c];
        }
        if (cc >= 0) {
            u32 a2 = accBefore;
            for (int bi = cc * 16 + 15; bi >= cc * 16; --bi) {
                a2 += lh[bi];
                if (a2 >= KCAND) { bs = bi; break; }
            }
        }
        bstar[b] = bs;
    }
}

// ---------- Kernel 3c (fallback): re-collect by bin filter ----------
__global__ void k3c_collect(const float* __restrict__ pred, u32* __restrict__ cntp,
                            u64* __restrict__ cand, const int* __restrict__ bstar,
                            const int* __restrict__ flag) {
    int b = blockIdx.y;
    if (!flag[b]) return;
    int bs = bstar[b];
    const float* p = pred + (size_t)b * NPRED * 85;
    int base = blockIdx.x * CHUNK;
    int end = base + CHUNK;
    for (int e = base + threadIdx.x; e < end; e += 256) {
        u32 n = (u32)e / NCC;
        u32 c = (u32)e - n * NCC;
        float obj = p[n * 85 + 4];
        float cv  = p[n * 85 + 5 + c];
        float s = obj * cv;
        bool take;
        if (bs < 0) take = (s > CONF);
        else {
            int ib = (int)((s - HIST_LO) * HIST_SCALE);
            if (ib > NBINS - 1) ib = NBINS - 1;
            take = (s > HIST_LO) && (ib >= bs);
        }
        if (take) {
            u32 pos = atomicAdd(&cntp[b * CNT_STRIDE], 1u);
            if (pos < CAPC) {
                u32 sb = __float_as_uint(s);
                cand[(size_t)b * CAPC + pos] = ((u64)sb << 32) | (u32)(~(u32)e);
            }
        }
    }
}

// ---------- Kernel 4: copy keys, bitonic sort desc, top-2048, gather boxes ----------
__global__ __launch_bounds__(1024) void k4_sort_gather(
        const float* __restrict__ pred, const u32* __restrict__ cntp,
        const u64* __restrict__ cand,
        float4* __restrict__ cbox, float* __restrict__ clsArr, float* __restrict__ scoreArr) {
    int b = blockIdx.x;
    __shared__ u64 keys[SORTN];
    u32 m = cntp[b * CNT_STRIDE];
    if (m > SORTN) m = SORTN;
    for (int i = threadIdx.x; i < SORTN; i += 1024)
        keys[i] = (i < (int)m) ? cand[(size_t)b * CAPC + i] : 0ULL;
    __syncthreads();
    for (int k = 2; k <= SORTN; k <<= 1) {
        for (int j = k >> 1; j > 0; j >>= 1) {
            for (int i = threadIdx.x; i < SORTN; i += 1024) {
                int ixj = i ^ j;
                if (ixj > i) {
                    u64 a = keys[i], bb = keys[ixj];
                    bool up = (i & k) == 0;
                    bool sw = up ? (a < bb) : (a > bb);
                    if (sw) { keys[i] = bb; keys[ixj] = a; }
                }
            }
            __syncthreads();
        }
    }
    const float* p = pred + (size_t)b * NPRED * 85;
    for (int t = threadIdx.x; t < KCAND; t += 1024) {
        u64 key = keys[t];
        float s = __uint_as_float((u32)(key >> 32));
        float4 cb; float cf; float sv;
        if (s > CONF) {
            u32 idx = ~(u32)key;
            u32 n = idx / NCC; u32 c = idx - n * NCC;
            float x = p[n * 85 + 0], y = p[n * 85 + 1];
            float w = p[n * 85 + 2], h = p[n * 85 + 3];
            float hw = w * 0.5f, hh = h * 0.5f;
            cb = make_float4(x - hw, y - hh, x + hw, y + hh);
            cf = (float)c; sv = s;
        } else {
            cb = make_float4(0.f, 0.f, 0.f, 0.f); cf = 0.f; sv = -1.f;
        }
        cbox[(size_t)b * KCAND + t] = cb;
        clsArr[(size_t)b * KCAND + t] = cf;
        scoreArr[(size_t)b * KCAND + t] = sv;
    }
}

// ---------- Kernel 5: IoU adjacency, class-match only (cross-class provably 0) ----------
__global__ __launch_bounds__(1024) void k5_iou(const float4* __restrict__ cbox,
                                               const float* __restrict__ clsArr,
                                               u64* __restrict__ over) {
    int blk = blockIdx.x;          // 32 img * 64 row-blocks
    int b = blk >> 6;
    int rowBase = (blk & 63) << 5; // 32 rows per block
    __shared__ float ox1[KCAND], oy1[KCAND], ox2[KCAND], oy2[KCAND], oar[KCAND], lcl[KCAND];
    for (int j = threadIdx.x; j < KCAND; j += 1024) {
        float4 cb = cbox[(size_t)b * KCAND + j];
        float cj = clsArr[(size_t)b * KCAND + j];
        ox1[j] = cb.x; oy1[j] = cb.y; ox2[j] = cb.z; oy2[j] = cb.w;
        oar[j] = (cb.z - cb.x) * (cb.w - cb.y);
        lcl[j] = cj;
    }
    __syncthreads();
    int w = threadIdx.x & 31;
    int r = threadIdx.x >> 5;
    int i = rowBase + r;
    float ci = lcl[i];
    float ix1 = ox1[i], iy1 = oy1[i], ix2 = ox2[i], iy2 = oy2[i], iar = oar[i];
    u64 bits = 0;
    int j0 = w << 6;
    for (int jb = 0; jb < 64; ++jb) {
        int jj = (jb + w) & 63;         // rotate to avoid LDS bank conflicts
        int j = j0 + jj;
        if (lcl[j] == ci) {             // same class only; backward/diag bits harmless
            float lx = fmaxf(ix1, ox1[j]);
            float ly = fmaxf(iy1, oy1[j]);
            float rx = fminf(ix2, ox2[j]);
            float ry = fminf(iy2, oy2[j]);
            float iw = rx - lx; if (iw < 0.f) iw = 0.f;
            float ih = ry - ly; if (ih < 0.f) ih = 0.f;
            float inter = iw * ih;
            float uni = iar + oar[j] - inter;
            float iou = inter / uni;     // NaN for degenerate -> false
            if (iou > IOU_T) bits |= (1ULL << jj);
        }
    }
    over[((size_t)b * KCAND + i) * 32 + w] = bits;
}

// ---------- Kernel 6: greedy suppression, chunked-LDS rows ----------
__global__ __launch_bounds__(64) void k6_nms_out(const float4* __restrict__ cbox,
                                                 const float* __restrict__ clsArr,
                                                 const float* __restrict__ scoreArr,
                                                 const u64* __restrict__ over,
                                                 float* __restrict__ out) {
    int b = blockIdx.x;
    int lane = threadIdx.x;
    __shared__ u64 keep[32];
    __shared__ u64 rowsf[64 * 32];       // 16 KB: one 64-candidate chunk of rows
    __shared__ unsigned short outl[MAXDET];
    const float* sc = scoreArr + (size_t)b * KCAND;
    for (int k = 0; k < 32; ++k) {
        u64 m = __ballot(sc[k * 64 + lane] > CONF);
        if (lane == k) keep[k] = m;
    }
    __syncthreads();
    int outc = 0;
    const u64* ov = over + (size_t)b * KCAND * 32;
    for (int w = 0; w < 32 && outc < MAXDET; ++w) {
        const u64* src = ov + (size_t)w * 64 * 32;
        for (int t = 0; t < 32; ++t) rowsf[lane + t * 64] = src[lane + t * 64];
        __syncthreads();
        u64 m = keep[w];
        while (m && outc < MAXDET) {
            int t = __builtin_ctzll(m);
            if (lane == 0) outl[outc] = (unsigned short)(w * 64 + t);
            outc++;
            if (lane < 32) keep[lane] &= ~rowsf[t * 32 + lane];
            __syncthreads();
            m = (t == 63) ? 0ULL : (keep[w] & (~0ULL << (t + 1)));
        }
        __syncthreads();
    }
    __syncthreads();
    float* ob = out + (size_t)b * MAXDET * 6;
    for (int slot = lane; slot < MAXDET; slot += 64) {
        float v0 = 0.f, v1 = 0.f, v2 = 0.f, v3 = 0.f, v4 = 0.f, v5 = 0.f;
        if (slot < outc) {
            int i = outl[slot];
            float4 cb = cbox[(size_t)b * KCAND + i];
            v0 = cb.x; v1 = cb.y; v2 = cb.z; v3 = cb.w;
            v4 = sc[i];
            v5 = clsArr[(size_t)b * KCAND + i];
        }
        ob[slot * 6 + 0] = v0; ob[slot * 6 + 1] = v1; ob[slot * 6 + 2] = v2;
        ob[slot * 6 + 3] = v3; ob[slot * 6 + 4] = v4; ob[slot * 6 + 5] = v5;
    }
}

extern "C" void kernel_launch(void* const* d_in, const int* in_sizes, int n_in,
                              void* d_out, int out_size, void* d_ws, size_t ws_size,
                              hipStream_t stream) {
    const float* pred = (const float*)d_in[0];
    float* out = (float*)d_out;
    uint8_t* ws = (uint8_t*)d_ws;

    u32* cntp   = (u32*)(ws + OFF_CNT);
    int* bstar  = (int*)(ws + OFF_BSTAR);
    int* flag   = (int*)(ws + OFF_FLAG);
    u64* cand   = (u64*)(ws + OFF_CAND);
    float4* cbox    = (float4*)(ws + OFF_CBOX);
    float* clsArr   = (float*)(ws + OFF_CLS);
    float* scoreArr = (float*)(ws + OFF_SCORE);
    u64* over   = (u64*)(ws + OFF_OVER);

    k0_init<<<5, 256, 0, stream>>>((u32*)(ws + OFF_CNT));   // 4.3 KB only

    dim3 g1(K1_GX, NBI);
    k1_collect<<<g1, 256, 0, stream>>>(pred, cntp, cand);
    k2_check<<<1, 64, 0, stream>>>(cntp, flag);
    k3ab_hist_thresh<<<NBI, 1024, 0, stream>>>(pred, bstar, flag);
    dim3 g3(252, NBI);
    k3c_collect<<<g3, 256, 0, stream>>>(pred, cntp, cand, bstar, flag);
    k4_sort_gather<<<NBI, 1024, 0, stream>>>(pred, cntp, cand, cbox, clsArr, scoreArr);
    k5_iou<<<NBI * 64, 1024, 0, stream>>>(cbox, clsArr, over);
    k6_nms_out<<<NBI, 64, 0, stream>>>(cbox, clsArr, scoreArr, over, out);
}

// Round 7
// 175.306 us; speedup vs baseline: 6.4282x; 1.3655x over previous
//
#include <hip/hip_runtime.h>
#include <stdint.h>

typedef unsigned long long u64;
typedef unsigned int u32;
typedef unsigned char u8;

#define NCC 80
#define NPRED 25200
#define NBI 32
#define NELEM (NPRED * NCC)   // 2016000
#define KCAND 2048
#define MAXDET 300
#define CONF 0.001f
#define IOU_T 0.6f
#define NBINS 4096
#define SORTN 4096
#define HIST_LO 0.5f
#define HIST_SCALE 8192.0f
#define COLLECT_T 0.946f      // E[count>T] ~ 2988/image, ~17 sigma inside [2048,4096]
#define ROWS_PER_BLK 256
#define K1_GX 99              // ceil(25200/256)
#define SLOT 128              // per-block candidate slots (mean ~30)
#define LBUF 512
#define BCNT_STRIDE 128
#define FCNT_STRIDE 32
#define FB_GX 63
#define FB_CHUNK 32000        // NELEM / 63

// workspace layout (bytes) — nothing needs pre-zeroing
static const size_t OFF_BCNT  = 0;                                    // 32*128*4 = 16384
static const size_t OFF_FCNT  = 16384;                                // 32*32*4 = 4096
static const size_t OFF_FLAG  = 20480;                                // 128
static const size_t OFF_BSTAR = 20608;                                // 128
static const size_t OFF_CAND  = 20736;                                // 32*99*128*8 = 3244032

// ---------- K1: row-scan + cooperative class-scan; per-block slots, no global atomics ----------
__global__ void k1_collect(const float* __restrict__ pred,
                           u32* __restrict__ bcnt, u64* __restrict__ cand) {
    int b = blockIdx.y;
    __shared__ u32 hotrow[ROWS_PER_BLK];
    __shared__ float hotobj[ROWS_PER_BLK];
    __shared__ u64 sbuf[LBUF];
    __shared__ u32 hq, sn;
    if (threadIdx.x == 0) { hq = 0; sn = 0; }
    __syncthreads();
    const float* p = pred + (size_t)b * NPRED * 85;
    int row = blockIdx.x * ROWS_PER_BLK + threadIdx.x;
    if (row < NPRED) {
        float obj = p[row * 85 + 4];
        if (obj > COLLECT_T) {            // cv < 1 so s > T requires obj > T
            u32 q = atomicAdd(&hq, 1u);
            hotrow[q] = (u32)row; hotobj[q] = obj;
        }
    }
    __syncthreads();
    u32 nh = hq;
    int wid = threadIdx.x >> 6, lane = threadIdx.x & 63;
    for (u32 q = (u32)wid; q < nh; q += 4) {
        u32 r = hotrow[q]; float obj = hotobj[q];
        const float* rp = p + (size_t)r * 85 + 5;
        #pragma unroll
        for (int t = 0; t < 2; ++t) {
            int c = lane + t * 64;
            if (c < NCC) {
                float s = obj * rp[c];
                if (s > COLLECT_T) {
                    u64 key = ((u64)__float_as_uint(s) << 32) | (u32)(~(u32)(r * NCC + (u32)c));
                    u32 pos = atomicAdd(&sn, 1u);
                    if (pos < LBUF) sbuf[pos] = key;
                    // pos >= LBUF: dropped, but sn>SLOT triggers fallback anyway
                }
            }
        }
    }
    __syncthreads();
    u32 nc = sn; u32 nw = nc < SLOT ? nc : SLOT;
    u64* dst = cand + ((size_t)b * K1_GX + blockIdx.x) * SLOT;
    for (u32 i = threadIdx.x; i < nw; i += 256) dst[i] = sbuf[i];
    if (threadIdx.x == 0) bcnt[b * BCNT_STRIDE + blockIdx.x] = nc;   // uncapped
}

// ---------- K2f: validity check + (flag-gated) LDS hist + threshold; one block/image ----------
__global__ __launch_bounds__(1024) void k2_fallback(const float* __restrict__ pred,
                                                    const u32* __restrict__ bcnt,
                                                    u32* __restrict__ fcnt,
                                                    int* __restrict__ flag,
                                                    int* __restrict__ bstar) {
    int b = blockIdx.x;
    __shared__ u32 lh[NBINS];
    __shared__ u32 csum[256];
    __shared__ u32 tot; __shared__ int bad;
    if (threadIdx.x == 0) { tot = 0; bad = 0; }
    __syncthreads();
    if (threadIdx.x < K1_GX) {
        u32 c = bcnt[b * BCNT_STRIDE + threadIdx.x];
        atomicAdd(&tot, c);
        if (c > SLOT) atomicExch(&bad, 1);
    }
    __syncthreads();
    u32 m = tot;
    int f = (m < KCAND || m > SORTN || bad) ? 1 : 0;
    if (threadIdx.x == 0) { flag[b] = f; if (f) fcnt[b * FCNT_STRIDE] = 0; }
    if (!f) return;
    // ---- heavy fallback path (never taken on this data) ----
    for (int i = threadIdx.x; i < NBINS; i += 1024) lh[i] = 0;
    __syncthreads();
    const float* p = pred + (size_t)b * NPRED * 85;
    for (int e = threadIdx.x; e < NELEM; e += 1024) {
        u32 n = (u32)e / NCC;
        u32 c = (u32)e - n * NCC;
        float obj = p[n * 85 + 4];
        if (obj > HIST_LO) {
            float s = obj * p[n * 85 + 5 + c];
            if (s > HIST_LO) {
                int ib = (int)((s - HIST_LO) * HIST_SCALE);
                if (ib > NBINS - 1) ib = NBINS - 1;
                atomicAdd(&lh[ib], 1u);
            }
        }
    }
    __syncthreads();
    if (threadIdx.x < 256) {
        u32 s = 0;
        for (int i = 0; i < 16; ++i) s += lh[threadIdx.x * 16 + i];
        csum[threadIdx.x] = s;
    }
    __syncthreads();
    if (threadIdx.x == 0) {
        int bs = -1; u32 acc = 0; int cc = -1; u32 accBefore = 0;
        for (int c = 255; c >= 0; --c) {
            if (acc + csum[c] >= KCAND) { cc = c; accBefore = acc; break; }
            acc += csum[c];
        }
        if (cc >= 0) {
            u32 a2 = accBefore;
            for (int bi = cc * 16 + 15; bi >= cc * 16; --bi) {
                a2 += lh[bi];
                if (a2 >= KCAND) { bs = bi; break; }
            }
        }
        bstar[b] = bs;
    }
}

// ---------- K3c (fallback, flag-gated): re-collect by bin filter ----------
__global__ void k3c_collect(const float* __restrict__ pred, u32* __restrict__ fcnt,
                            u64* __restrict__ cand, const int* __restrict__ bstar,
                            const int* __restrict__ flag) {
    int b = blockIdx.y;
    if (!flag[b]) return;
    int bs = bstar[b];
    const float* p = pred + (size_t)b * NPRED * 85;
    int base = blockIdx.x * FB_CHUNK;
    int end = base + FB_CHUNK;
    for (int e = base + threadIdx.x; e < end; e += 256) {
        u32 n = (u32)e / NCC;
        u32 c = (u32)e - n * NCC;
        float obj = p[n * 85 + 4];
        float s = obj * p[n * 85 + 5 + c];
        bool take;
        if (bs < 0) take = (s > CONF);
        else {
            int ib = (int)((s - HIST_LO) * HIST_SCALE);
            if (ib > NBINS - 1) ib = NBINS - 1;
            take = (s > HIST_LO) && (ib >= bs);
        }
        if (take) {
            u32 pos = atomicAdd(&fcnt[b * FCNT_STRIDE], 1u);
            if (pos < (u32)(K1_GX * SLOT)) {
                cand[(size_t)b * K1_GX * SLOT + pos] =
                    ((u64)__float_as_uint(s) << 32) | (u32)(~(u32)e);
            }
        }
    }
}

// ---------- K456: compact -> sort -> gather -> class-group -> per-class NMS -> output ----------
__global__ __launch_bounds__(1024) void k456_nms(const float* __restrict__ pred,
                                                 const u32* __restrict__ bcnt,
                                                 const u32* __restrict__ fcnt,
                                                 const int* __restrict__ flag,
                                                 const u64* __restrict__ cand,
                                                 float* __restrict__ out) {
    int b = blockIdx.x;
    int tid = threadIdx.x;
    __shared__ u64 keys[SORTN];          // 32 KB, sorted desc; survives to the end (scores)
    __shared__ float bx1[KCAND], by1[KCAND], bx2[KCAND], by2[KCAND];  // 32 KB raw coords
    __shared__ u32 skey[KCAND];          // 8 KB: (cls<<12)|rank
    __shared__ u32 cstart[NCC + 1];
    __shared__ u32 pfx[K1_GX + 1];
    __shared__ u8 keepA[KCAND];
    __shared__ u8 clsA[KCAND];
    __shared__ u32 tsum[1024];

    // ---- load & compact candidates into keys[0..] ----
    if (flag[b]) {
        u32 m = fcnt[b * FCNT_STRIDE]; if (m > SORTN) m = SORTN;
        for (int i = tid; i < SORTN; i += 1024)
            keys[i] = (i < (int)m) ? cand[(size_t)b * K1_GX * SLOT + i] : 0ULL;
    } else {
        if (tid == 0) {
            u32 a = 0;
            for (int s = 0; s < K1_GX; ++s) { pfx[s] = a; a += bcnt[b * BCNT_STRIDE + s]; }
            pfx[K1_GX] = a;
        }
        for (int i = tid; i < SORTN; i += 1024) keys[i] = 0ULL;
        __syncthreads();
        for (int t = tid; t < K1_GX * SLOT; t += 1024) {
            int sb = t / SLOT, j = t - sb * SLOT;
            u32 c = bcnt[b * BCNT_STRIDE + sb]; if (c > SLOT) c = SLOT;
            if ((u32)j < c)
                keys[pfx[sb] + j] = cand[((size_t)b * K1_GX + sb) * SLOT + j];
        }
    }
    __syncthreads();
    // ---- bitonic sort u64 desc ----
    for (int k = 2; k <= SORTN; k <<= 1) {
        for (int j = k >> 1; j > 0; j >>= 1) {
            for (int i = tid; i < SORTN; i += 1024) {
                int ixj = i ^ j;
                if (ixj > i) {
                    u64 a = keys[i], bb = keys[ixj];
                    bool up = (i & k) == 0;
                    if (up ? (a < bb) : (a > bb)) { keys[i] = bb; keys[ixj] = a; }
                }
            }
            __syncthreads();
        }
    }
    // ---- gather top-2048 boxes (raw coords), class, build class-sort keys ----
    const float* p = pred + (size_t)b * NPRED * 85;
    for (int t = tid; t < KCAND; t += 1024) {
        u64 key = keys[t];
        float s = __uint_as_float((u32)(key >> 32));
        if (s > CONF) {
            u32 idx = ~(u32)key;
            u32 n = idx / NCC; u32 c = idx - n * NCC;
            float x = p[n * 85 + 0], y = p[n * 85 + 1];
            float w = p[n * 85 + 2], h = p[n * 85 + 3];
            float hw = w * 0.5f, hh = h * 0.5f;
            bx1[t] = x - hw; by1[t] = y - hh; bx2[t] = x + hw; by2[t] = y + hh;
            clsA[t] = (u8)c;
            skey[t] = (c << 12) | (u32)t;
        } else {
            bx1[t] = 0.f; by1[t] = 0.f; bx2[t] = 0.f; by2[t] = 0.f;
            clsA[t] = 0;
            skey[t] = (u32)t;   // class 0, high rank -> end of class-0 list, invalid
        }
    }
    __syncthreads();
    // ---- bitonic sort u32 asc: class-major, rank-minor ----
    for (int k = 2; k <= KCAND; k <<= 1) {
        for (int j = k >> 1; j > 0; j >>= 1) {
            for (int i = tid; i < KCAND; i += 1024) {
                int ixj = i ^ j;
                if (ixj > i) {
                    u32 a = skey[i], bb = skey[ixj];
                    bool up = (i & k) == 0;
                    if (up ? (a > bb) : (a < bb)) { skey[i] = bb; skey[ixj] = a; }
                }
            }
            __syncthreads();
        }
    }
    // ---- class starts ----
    for (int t = tid; t < KCAND; t += 1024) {
        int c = (int)(skey[t] >> 12);
        int cp = (t == 0) ? -1 : (int)(skey[t - 1] >> 12);
        if (c != cp) for (int cc = cp + 1; cc <= c; ++cc) cstart[cc] = (u32)t;
        if (t == KCAND - 1) for (int cc = c + 1; cc <= NCC; ++cc) cstart[cc] = KCAND;
    }
    __syncthreads();
    // ---- per-class NMS: wave wv handles classes wv, wv+16, ... ----
    int wv = tid >> 6, lane = tid & 63;
    for (int c = wv; c < NCC; c += 16) {
        int st = (int)cstart[c], en = (int)cstart[c + 1];
        int nc = en - st;
        if (nc <= 0) continue;
        float off = (float)c * 4096.0f;
        if (nc <= 64) {
            bool has = lane < nc;
            u32 r = 0; float X1 = 0, Y1 = 0, X2 = 0, Y2 = 0, AR = 0, sc = -1.f;
            if (has) {
                r = skey[st + lane] & 0xFFFu;
                X1 = bx1[r] + off; Y1 = by1[r] + off; X2 = bx2[r] + off; Y2 = by2[r] + off;
                AR = (X2 - X1) * (Y2 - Y1);
                sc = __uint_as_float((u32)(keys[r] >> 32));
            }
            u64 kb = __ballot(has && sc > CONF);
            u64 work = kb;
            while (work) {
                int i = __builtin_ctzll(work); work &= work - 1;
                if (!((kb >> i) & 1)) continue;
                u32 ri = skey[st + i] & 0xFFFu;           // LDS broadcast
                float ix1 = bx1[ri] + off, iy1 = by1[ri] + off;
                float ix2 = bx2[ri] + off, iy2 = by2[ri] + off;
                float iar = (ix2 - ix1) * (iy2 - iy1);
                float lx = fmaxf(ix1, X1), ly = fmaxf(iy1, Y1);
                float rx = fminf(ix2, X2), ry = fminf(iy2, Y2);
                float iw = fmaxf(rx - lx, 0.f), ih = fmaxf(ry - ly, 0.f);
                float inter = iw * ih;
                float iou = inter / (iar + AR - inter);
                u64 sup = __ballot(has && iou > IOU_T);
                sup &= (i == 63) ? 0ULL : (~0ULL << (i + 1));
                kb &= ~sup;
                work &= kb;
            }
            if (has) keepA[r] = (u8)((kb >> lane) & 1);
        } else {
            // generic path (nc>64): wave-synchronous, LDS-resident keep flags (never hit in practice)
            int S = (nc + 63) >> 6;
            for (int s = 0; s < S; ++s) {
                int pos = st + s * 64 + lane;
                if (pos < en) {
                    u32 r = skey[pos] & 0xFFFu;
                    float sc = __uint_as_float((u32)(keys[r] >> 32));
                    keepA[r] = (u8)(sc > CONF);
                }
            }
            for (int i = 0; i < nc; ++i) {
                u32 ri = skey[st + i] & 0xFFFu;
                if (!keepA[ri]) continue;
                float ix1 = bx1[ri] + off, iy1 = by1[ri] + off;
                float ix2 = bx2[ri] + off, iy2 = by2[ri] + off;
                float iar = (ix2 - ix1) * (iy2 - iy1);
                for (int s = 0; s < S; ++s) {
                    int pos = st + s * 64 + lane;
                    if (pos < en && pos > st + i) {
                        u32 r = skey[pos] & 0xFFFu;
                        if (keepA[r]) {
                            float X1 = bx1[r] + off, Y1 = by1[r] + off;
                            float X2 = bx2[r] + off, Y2 = by2[r] + off;
                            float AR = (X2 - X1) * (Y2 - Y1);
                            float lx = fmaxf(ix1, X1), ly = fmaxf(iy1, Y1);
                            float rx = fminf(ix2, X2), ry = fminf(iy2, Y2);
                            float iw = fmaxf(rx - lx, 0.f), ih = fmaxf(ry - ly, 0.f);
                            float inter = iw * ih;
                            float iou = inter / (iar + AR - inter);
                            if (iou > IOU_T) keepA[r] = 0;
                        }
                    }
                }
            }
        }
    }
    __syncthreads();
    // ---- rank-order compaction; first 300 kept -> output ----
    int kA = (int)keepA[2 * tid];
    int kB = (int)keepA[2 * tid + 1];
    tsum[tid] = (u32)(kA + kB);
    __syncthreads();
    for (int offd = 1; offd < 1024; offd <<= 1) {
        u32 v = (tid >= offd) ? tsum[tid - offd] : 0u;
        __syncthreads();
        tsum[tid] += v;
        __syncthreads();
    }
    u32 pre = tsum[tid] - (u32)(kA + kB);   // exclusive prefix over thread pairs
    float* ob = out + (size_t)b * MAXDET * 6;
    for (int i = tid; i < MAXDET * 6; i += 1024) ob[i] = 0.f;
    __syncthreads();
    if (kA && pre < MAXDET) {
        int r = 2 * tid; u32 slot = pre;
        ob[slot * 6 + 0] = bx1[r]; ob[slot * 6 + 1] = by1[r];
        ob[slot * 6 + 2] = bx2[r]; ob[slot * 6 + 3] = by2[r];
        ob[slot * 6 + 4] = __uint_as_float((u32)(keys[r] >> 32));
        ob[slot * 6 + 5] = (float)clsA[r];
    }
    if (kB && pre + (u32)kA < MAXDET) {
        int r = 2 * tid + 1; u32 slot = pre + (u32)kA;
        ob[slot * 6 + 0] = bx1[r]; ob[slot * 6 + 1] = by1[r];
        ob[slot * 6 + 2] = bx2[r]; ob[slot * 6 + 3] = by2[r];
        ob[slot * 6 + 4] = __uint_as_float((u32)(keys[r] >> 32));
        ob[slot * 6 + 5] = (float)clsA[r];
    }
}

extern "C" void kernel_launch(void* const* d_in, const int* in_sizes, int n_in,
                              void* d_out, int out_size, void* d_ws, size_t ws_size,
                              hipStream_t stream) {
    const float* pred = (const float*)d_in[0];
    float* out = (float*)d_out;
    uint8_t* ws = (uint8_t*)d_ws;

    u32* bcnt  = (u32*)(ws + OFF_BCNT);
    u32* fcnt  = (u32*)(ws + OFF_FCNT);
    int* flag  = (int*)(ws + OFF_FLAG);
    int* bstar = (int*)(ws + OFF_BSTAR);
    u64* cand  = (u64*)(ws + OFF_CAND);

    dim3 g1(K1_GX, NBI);
    k1_collect<<<g1, 256, 0, stream>>>(pred, bcnt, cand);
    k2_fallback<<<NBI, 1024, 0, stream>>>(pred, bcnt, fcnt, flag, bstar);
    dim3 g3(FB_GX, NBI);
    k3c_collect<<<g3, 256, 0, stream>>>(pred, fcnt, cand, bstar, flag);
    k456_nms<<<NBI, 1024, 0, stream>>>(pred, bcnt, fcnt, flag, cand, out);
}